// Round 7
// baseline (1131.346 us; speedup 1.0000x reference)
//
#include <hip/hip_runtime.h>
#include <hip/hip_bf16.h>
#include <stdint.h>

#define B_ 2
#define S_ 4096
#define D_ 768
#define H_ 12
#define DH_ 64
#define L_ 2
#define W_ 256
#define G_ 64
#define FF_ 3072
#define C_ 7
#define SEP_ 2
#define NEG_ (-1000000000.0f)
#define NC_ 16

typedef __attribute__((ext_vector_type(8))) short short8;
typedef __attribute__((ext_vector_type(4))) float f32x4;

__device__ __forceinline__ float bfu2f(unsigned short u) {
    return __uint_as_float(((unsigned int)u) << 16);
}
__device__ __forceinline__ unsigned short f2bfu(float f) {
    unsigned int x = __float_as_uint(f);
    unsigned int r = (x + 0x7fffu + ((x >> 16) & 1u)) >> 16;
    return (unsigned short)r;
}
// gelu(tanh approx): 0.5*v*(1+tanh(c)) == v * sigmoid(2c)  (exact identity)
__device__ __forceinline__ float gelu_tanh(float v) {
    float u = 1.5957691216057308f * v + 0.0713548162726f * v * v * v;
    return v / (1.0f + __expf(-u));
}

// async global->LDS, 16B per lane. LDS dest must be wave-uniform base (HW adds lane*16).
__device__ __forceinline__ void gl16(const unsigned short* g, unsigned short* l) {
    __builtin_amdgcn_global_load_lds(
        (const __attribute__((address_space(1))) unsigned int*)g,
        (__attribute__((address_space(3))) unsigned int*)l,
        16, 0, 0);
}

// XCD-banded block remap (bijective; requires ny%8==0, true for all launches here).
__device__ __forceinline__ void xcd_remap(int& bx, int& by, int& bz) {
    int nx = gridDim.x, ny = gridDim.y, nz = gridDim.z;
    int flat = bx + nx * (by + ny * bz);
    int nxz = nx * nz;
    int xcd = flat & 7;
    int n = flat >> 3;
    int band = n / nxz;
    int r = n - band * nxz;
    by = xcd * (ny >> 3) + band;
    bz = r / nx;
    bx = r - bz * nx;
}

// ===== V staging into k-block-swizzled d-major LDS tile =====
// Layout: element (d, k) of a 64x64 V tile lives at Vt[d][ ((k>>3) ^ ((d>>3)&7))*8 + (k&7) ].
#define STAGE_V_SWZ(Vt, v0v, v1v, sr, sc)                                              \
    {                                                                                  \
        unsigned me0[4] = {v0v.x, v0v.y, v0v.z, v0v.w};                                \
        unsigned me1[4] = {v1v.x, v1v.y, v1v.z, v1v.w};                                \
        unsigned pc0[4], pc1[4];                                                       \
        _Pragma("unroll")                                                              \
        for (int i_ = 0; i_ < 4; i_++) {                                               \
            pc0[i_] = __shfl_xor(me0[i_], 4);                                          \
            pc1[i_] = __shfl_xor(me1[i_], 4);                                          \
        }                                                                              \
        int odd_ = (sr) & 1;                                                           \
        int scp_ = odd_ ? (sc) + 4 : (sc);                                             \
        int dbase_ = scp_ << 3;                                                        \
        int kcol_ = (((sr) >> 3) ^ scp_) << 3;                                         \
        int koff_ = kcol_ + ((sr) & 6);                                                \
        _Pragma("unroll")                                                              \
        for (int i_ = 0; i_ < 4; i_++) {                                               \
            unsigned lo_ = odd_ ? pc1[i_] : me0[i_];                                   \
            unsigned hi_ = odd_ ? me1[i_] : pc0[i_];                                   \
            unsigned w0_ = (lo_ & 0xffffu) | (hi_ << 16);                              \
            unsigned w1_ = (lo_ >> 16) | (hi_ & 0xffff0000u);                          \
            *(unsigned*)&Vt[dbase_ + 2 * i_][koff_] = w0_;                             \
            *(unsigned*)&Vt[dbase_ + 2 * i_ + 1][koff_] = w1_;                         \
        }                                                                              \
    }

// read the PV B-fragment (8 k-slots for column d=row) from the swizzled tile
#define READ_V_SWZ(Vt, row, hh)                                                        \
    (*(const short8*)&Vt[row][(((hh) * 4 + quad) ^ (((row) >> 3) & 7)) << 3])

// ================= 256x256 8-phase GEMM core (T2+T3+T4+T5 stack) =================
#define GEMM256_CORE(APTR, BTPTR, KVAL, KBEG, KPER)                                    \
    __shared__ __align__(16) unsigned short Lb[2 * 2 * 2 * 8192];                      \
    const int tid = threadIdx.x;                                                       \
    const int wave = tid >> 6, lane = tid & 63;                                        \
    const int l16 = lane & 15, quad = lane >> 4;                                       \
    const int wr = wave >> 2, wc = wave & 3;                                           \
    const int cw = (wc & 1) << 6;                                                      \
    const int srow = tid >> 3;                                                         \
    const int scol8 = (lane & 7) ^ ((lane >> 3) & 7);                                  \
    const int so0 = (quad ^ (l16 & 7)) << 3;                                           \
    const int so1 = so0 ^ 32;                                                          \
    f32x4 acc[8][4];                                                                   \
    _Pragma("unroll") for (int i_ = 0; i_ < 8; i_++)                                   \
        _Pragma("unroll") for (int j_ = 0; j_ < 4; j_++)                               \
            acc[i_][j_] = (f32x4){0.f, 0.f, 0.f, 0.f};                                 \
    auto stA = [&](int d, int h, int kofs) {                                           \
        const unsigned short* g = (APTR) +                                             \
            (size_t)(m0 + h * 128 + srow) * (KVAL) + kofs + scol8 * 8;                 \
        unsigned short* dst = Lb + (d * 4 + h) * 8192 + wave * 512;                    \
        gl16(g, dst);                                                                  \
        gl16(g + (size_t)64 * (KVAL), dst + 4096);                                     \
    };                                                                                 \
    auto stB = [&](int d, int h, int kofs) {                                           \
        const unsigned short* g = (BTPTR) +                                            \
            (size_t)(n0 + h * 128 + srow) * (KVAL) + kofs + scol8 * 8;                 \
        unsigned short* dst = Lb + (d * 4 + 2 + h) * 8192 + wave * 512;                \
        gl16(g, dst);                                                                  \
        gl16(g + (size_t)64 * (KVAL), dst + 4096);                                     \
    };                                                                                 \
    auto lda = [&](short8 av[4][2], int d, int mh) {                                   \
        const unsigned short* Ah = Lb + (d * 4 + wr) * 8192;                           \
        _Pragma("unroll") for (int fi = 0; fi < 4; fi++) {                             \
            int rl = mh * 64 + fi * 16 + l16;                                          \
            av[fi][0] = *(const short8*)(Ah + rl * 64 + so0);                          \
            av[fi][1] = *(const short8*)(Ah + rl * 64 + so1);                          \
        }                                                                              \
    };                                                                                 \
    auto ldb = [&](short8 bv[2][2], int d, int nh) {                                   \
        const unsigned short* Bh = Lb + (d * 4 + 2 + (wc >> 1)) * 8192;                \
        _Pragma("unroll") for (int j = 0; j < 2; j++) {                                \
            int rl = cw + nh * 32 + j * 16 + l16;                                      \
            bv[j][0] = *(const short8*)(Bh + rl * 64 + so0);                           \
            bv[j][1] = *(const short8*)(Bh + rl * 64 + so1);                           \
        }                                                                              \
    };                                                                                 \
    auto mm = [&](short8 av[4][2], short8 bv[2][2], int mh, int nh) {                  \
        _Pragma("unroll") for (int fi = 0; fi < 4; fi++)                               \
            _Pragma("unroll") for (int j = 0; j < 2; j++)                              \
                _Pragma("unroll") for (int kk = 0; kk < 2; kk++)                       \
                    acc[mh * 4 + fi][nh * 2 + j] =                                     \
                        __builtin_amdgcn_mfma_f32_16x16x32_bf16(                       \
                            av[fi][kk], bv[j][kk], acc[mh * 4 + fi][nh * 2 + j],       \
                            0, 0, 0);                                                  \
    };                                                                                 \
    stA(0, 0, (KBEG)); stA(0, 1, (KBEG)); stB(0, 0, (KBEG)); stB(0, 1, (KBEG));        \
    stB(1, 0, (KBEG) + 64); stB(1, 1, (KBEG) + 64);                                    \
    asm volatile("s_waitcnt vmcnt(4)" ::: "memory");                                   \
    __builtin_amdgcn_s_barrier();                                                      \
    {                                                                                  \
        const int NI = (KPER) >> 7;                                                    \
        short8 a[4][2], b0v[2][2], b1v[2][2];                                          \
        for (int it = 0; it < NI; it++) {                                              \
            int kof = (KBEG) + (it << 7);                                              \
            bool pre = (it + 1 < NI);                                                  \
            lda(a, 0, 0); ldb(b0v, 0, 0);                                              \
            stA(1, 0, kof + 64);                                                       \
            __builtin_amdgcn_s_barrier();                                              \
            __builtin_amdgcn_s_setprio(1); mm(a, b0v, 0, 0);                           \
            __builtin_amdgcn_s_setprio(0); __builtin_amdgcn_s_barrier();               \
            ldb(b1v, 0, 1); stA(1, 1, kof + 64);                                       \
            __builtin_amdgcn_s_barrier();                                              \
            __builtin_amdgcn_s_setprio(1); mm(a, b1v, 0, 1);                           \
            __builtin_amdgcn_s_setprio(0); __builtin_amdgcn_s_barrier();               \
            lda(a, 0, 1);                                                              \
            if (pre) stB(0, 0, kof + 128);                                             \
            __builtin_amdgcn_s_barrier();                                              \
            __builtin_amdgcn_s_setprio(1); mm(a, b1v, 1, 1);                           \
            __builtin_amdgcn_s_setprio(0); __builtin_amdgcn_s_barrier();               \
            if (pre) { stB(0, 1, kof + 128);                                           \
                       asm volatile("s_waitcnt vmcnt(4)" ::: "memory"); }              \
            else     { asm volatile("s_waitcnt vmcnt(0)" ::: "memory"); }              \
            __builtin_amdgcn_s_barrier();                                              \
            __builtin_amdgcn_s_setprio(1); mm(a, b0v, 1, 0);                           \
            __builtin_amdgcn_s_setprio(0); __builtin_amdgcn_s_barrier();               \
            lda(a, 1, 0); ldb(b0v, 1, 0);                                              \
            if (pre) stA(0, 0, kof + 128);                                             \
            __builtin_amdgcn_s_barrier();                                              \
            __builtin_amdgcn_s_setprio(1); mm(a, b0v, 0, 0);                           \
            __builtin_amdgcn_s_setprio(0); __builtin_amdgcn_s_barrier();               \
            ldb(b1v, 1, 1);                                                            \
            if (pre) stA(0, 1, kof + 128);                                             \
            __builtin_amdgcn_s_barrier();                                              \
            __builtin_amdgcn_s_setprio(1); mm(a, b1v, 0, 1);                           \
            __builtin_amdgcn_s_setprio(0); __builtin_amdgcn_s_barrier();               \
            lda(a, 1, 1);                                                              \
            if (pre) stB(1, 0, kof + 192);                                             \
            __builtin_amdgcn_s_barrier();                                              \
            __builtin_amdgcn_s_setprio(1); mm(a, b1v, 1, 1);                           \
            __builtin_amdgcn_s_setprio(0); __builtin_amdgcn_s_barrier();               \
            if (pre) { stB(1, 1, kof + 192);                                           \
                       asm volatile("s_waitcnt vmcnt(4)" ::: "memory"); }              \
            __builtin_amdgcn_s_barrier();                                              \
            __builtin_amdgcn_s_setprio(1); mm(a, b0v, 1, 0);                           \
            __builtin_amdgcn_s_setprio(0); __builtin_amdgcn_s_barrier();               \
        }                                                                              \
    }

// ---------------- 256^2 8-phase GEMM, generic epilogue ----------------
__global__ __launch_bounds__(512, 1) void k_gemm256_nt(
    const unsigned short* __restrict__ A, const unsigned short* __restrict__ Wt,
    const float* __restrict__ bias, float* __restrict__ Cf, float* __restrict__ Cf2,
    unsigned short* __restrict__ Cb, int M, int N, int K, int act) {
    int bx = blockIdx.x, by = blockIdx.y, bz = blockIdx.z;
    xcd_remap(bx, by, bz);
    int m0 = by << 8, n0 = bx << 8;
    int slice = bz;
    int kper = K / gridDim.z;
    int kbeg = slice * kper;
    GEMM256_CORE(A, Wt, K, kbeg, kper);
    float bj[4];
#pragma unroll
    for (int nj = 0; nj < 4; nj++)
        bj[nj] = (slice == 0) ? bias[n0 + (wc << 6) + nj * 16 + l16] : 0.f;
    float* outp = (slice == 0) ? Cf : Cf2;
#pragma unroll
    for (int mi = 0; mi < 8; mi++)
#pragma unroll
        for (int nj = 0; nj < 4; nj++) {
            int col = n0 + (wc << 6) + nj * 16 + l16;
#pragma unroll
            for (int rr = 0; rr < 4; rr++) {
                int row = m0 + (wr << 7) + mi * 16 + quad * 4 + rr;
                float v = acc[mi][nj][rr] + bj[nj];
                if (act) v = gelu_tanh(v);
                if (outp) outp[(size_t)row * N + col] = v;
                else      Cb[(size_t)row * N + col] = f2bfu(v);
            }
        }
}

// ---------------- 256^2 8-phase fused qkv5, head-major bf16 out ----------------
struct P5 {
    const unsigned short* Wt[5];
    const float* Wf[5];
    const float* bias[5];
    unsigned short* out[5];
};
__global__ __launch_bounds__(512, 1) void k_qkv5_256(
    const unsigned short* __restrict__ A, P5 p) {
    int bx = blockIdx.x, by = blockIdx.y, bz = blockIdx.z;
    xcd_remap(bx, by, bz);
    const unsigned short* __restrict__ Wt = p.Wt[bz];
    const float* __restrict__ bias = p.bias[bz];
    unsigned short* __restrict__ Cb = p.out[bz];
    const int K = D_;
    int m0 = by << 8, n0 = bx << 8;
    GEMM256_CORE(A, Wt, K, 0, K);
    float bj[4];
#pragma unroll
    for (int nj = 0; nj < 4; nj++) bj[nj] = bias[n0 + (wc << 6) + nj * 16 + l16];
#pragma unroll
    for (int mi = 0; mi < 8; mi++)
#pragma unroll
        for (int nj = 0; nj < 4; nj++) {
            int col = n0 + (wc << 6) + nj * 16 + l16;
#pragma unroll
            for (int rr = 0; rr < 4; rr++) {
                int row = m0 + (wr << 7) + mi * 16 + quad * 4 + rr;
                float v = acc[mi][nj][rr] + bj[nj];
                size_t adr = ((((size_t)(row >> 12)) * H_ + (col >> 6)) * S_ +
                              (row & (S_ - 1))) * DH_ + (col & 63);
                Cb[adr] = f2bfu(v);
            }
        }
}

// ---------------- legacy 128^2 helpers (fallback when no weight workspace) --------
#define GEMM_COMPUTE(Ab, Bb)                                                             \
    {                                                                                    \
        short8 af[4], bf[4];                                                             \
        _Pragma("unroll")                                                                \
        for (int i_ = 0; i_ < 4; i_++)                                                   \
            af[i_] = *(const short8*)&(Ab)[(wm + i_ * 16 + l16) * 32 + quad * 8];        \
        _Pragma("unroll")                                                                \
        for (int j_ = 0; j_ < 4; j_++)                                                   \
            bf[j_] = *(const short8*)&(Bb)[(wn + j_ * 16 + l16) * 32 + quad * 8];        \
        _Pragma("unroll")                                                                \
        for (int i_ = 0; i_ < 4; i_++)                                                   \
            _Pragma("unroll")                                                            \
            for (int j_ = 0; j_ < 4; j_++)                                               \
                acc[i_][j_] = __builtin_amdgcn_mfma_f32_16x16x32_bf16(af[i_], bf[j_],    \
                                                                      acc[i_][j_], 0, 0, 0); \
    }

#define WAIT_VM0_BARRIER()                                   \
    {                                                        \
        asm volatile("s_waitcnt vmcnt(0)" ::: "memory");     \
        __builtin_amdgcn_s_barrier();                        \
    }

// ---------------- merged weight convert+transpose (8 ops in one launch) ----------------
// op table: src [L][K][N] f32 -> dst [L][N][K] bf16 at per-layer stride PLs
struct WT8 {
    const float* src[8];
    unsigned short* dst[8];
    int K[8], N[8];
    int cum[9];
};
__global__ __launch_bounds__(256) void k_wtrans_all(WT8 p, size_t PLs) {
    int blk = blockIdx.x;
    int op = 0;
#pragma unroll
    for (int i = 0; i < 7; i++) op += (blk >= p.cum[i + 1]) ? 1 : 0;
    int local = blk - p.cum[op];
    int K = p.K[op], N = p.N[op];
    int nx = N >> 5, ny = K >> 5;
    int l = local / (nx * ny);
    int rem = local - l * (nx * ny);
    int bxx = rem % nx, byy = rem / nx;
    const float* src = p.src[op] + (size_t)l * K * N;
    unsigned short* dst = p.dst[op] + (size_t)l * PLs;
    __shared__ unsigned short tile[32][36];
    int t = threadIdx.x;
    int r = t >> 3, c4 = (t & 7) << 2;
    int k0 = byy << 5, n0 = bxx << 5;
    float4 v = *(const float4*)(src + (size_t)(k0 + r) * N + n0 + c4);
    tile[c4 + 0][r] = f2bfu(v.x);
    tile[c4 + 1][r] = f2bfu(v.y);
    tile[c4 + 2][r] = f2bfu(v.z);
    tile[c4 + 3][r] = f2bfu(v.w);
    __syncthreads();
    ushort4 o;
    o.x = tile[r][c4 + 0]; o.y = tile[r][c4 + 1];
    o.z = tile[r][c4 + 2]; o.w = tile[r][c4 + 3];
    *(ushort4*)(dst + (size_t)(n0 + r) * K + k0 + c4) = o;
}

// ---------------- embedding + LN: one wave per row ----------------
__global__ __launch_bounds__(256) void k_embed_ln(
    const int* __restrict__ ids, const float* __restrict__ etok,
    const float* __restrict__ epos, const float* __restrict__ lns,
    const float* __restrict__ lnb, float* __restrict__ x,
    unsigned short* __restrict__ xb) {
    int row = (blockIdx.x << 2) + (threadIdx.x >> 6);
    int lane = threadIdx.x & 63;
    int s = row & (S_ - 1);
    int id = ids[row];
    const float4* ep = (const float4*)(etok + (size_t)id * D_);
    const float4* pp = (const float4*)(epos + (size_t)s * D_);
    float4 a[3];
    float sum = 0.f, sum2 = 0.f;
#pragma unroll
    for (int i = 0; i < 3; i++) {
        float4 ev = ep[lane + i * 64];
        float4 pv = pp[lane + i * 64];
        ev.x += pv.x; ev.y += pv.y; ev.z += pv.z; ev.w += pv.w;
        a[i] = ev;
        sum  += ev.x + ev.y + ev.z + ev.w;
        sum2 += ev.x * ev.x + ev.y * ev.y + ev.z * ev.z + ev.w * ev.w;
    }
#pragma unroll
    for (int off = 1; off < 64; off <<= 1) {
        sum += __shfl_xor(sum, off);
        sum2 += __shfl_xor(sum2, off);
    }
    float mean = sum * (1.0f / D_);
    float var = sum2 * (1.0f / D_) - mean * mean;
    float rs = rsqrtf(var + 1e-5f);
    float4* xp = (float4*)(x + (size_t)row * D_);
#pragma unroll
    for (int i = 0; i < 3; i++) {
        float4 g = *(const float4*)(lns + lane * 4 + i * 256);
        float4 bb = *(const float4*)(lnb + lane * 4 + i * 256);
        float4 v;
        v.x = (a[i].x - mean) * rs * g.x + bb.x;
        v.y = (a[i].y - mean) * rs * g.y + bb.y;
        v.z = (a[i].z - mean) * rs * g.z + bb.z;
        v.w = (a[i].w - mean) * rs * g.w + bb.w;
        xp[lane + i * 64] = v;
        ushort4 u; u.x = f2bfu(v.x); u.y = f2bfu(v.y); u.z = f2bfu(v.z); u.w = f2bfu(v.w);
        *(ushort4*)(xb + (size_t)row * D_ + lane * 4 + i * 256) = u;
    }
}

// ---------------- residual add + LN (x += y [+ y2]), one wave per row ----------------
__global__ __launch_bounds__(256) void k_add_ln(
    float* __restrict__ x, const float* __restrict__ y, const float* __restrict__ y2,
    const float* __restrict__ lns, const float* __restrict__ lnb,
    unsigned short* __restrict__ xb) {
    int row = (blockIdx.x << 2) + (threadIdx.x >> 6);
    int lane = threadIdx.x & 63;
    float4* xp = (float4*)(x + (size_t)row * D_);
    const float4* yp = (const float4*)(y + (size_t)row * D_);
    const float4* y2p = y2 ? (const float4*)(y2 + (size_t)row * D_) : nullptr;
    float4 a[3];
    float sum = 0.f, sum2 = 0.f;
#pragma unroll
    for (int i = 0; i < 3; i++) {
        float4 xv = xp[lane + i * 64];
        float4 yv = yp[lane + i * 64];
        xv.x += yv.x; xv.y += yv.y; xv.z += yv.z; xv.w += yv.w;
        if (y2p) {
            float4 zv = y2p[lane + i * 64];
            xv.x += zv.x; xv.y += zv.y; xv.z += zv.z; xv.w += zv.w;
        }
        a[i] = xv;
        sum  += xv.x + xv.y + xv.z + xv.w;
        sum2 += xv.x * xv.x + xv.y * xv.y + xv.z * xv.z + xv.w * xv.w;
    }
#pragma unroll
    for (int off = 1; off < 64; off <<= 1) {
        sum += __shfl_xor(sum, off);
        sum2 += __shfl_xor(sum2, off);
    }
    float mean = sum * (1.0f / D_);
    float var = sum2 * (1.0f / D_) - mean * mean;
    float rs = rsqrtf(var + 1e-5f);
#pragma unroll
    for (int i = 0; i < 3; i++) {
        float4 g = *(const float4*)(lns + lane * 4 + i * 256);
        float4 bb = *(const float4*)(lnb + lane * 4 + i * 256);
        float4 v;
        v.x = (a[i].x - mean) * rs * g.x + bb.x;
        v.y = (a[i].y - mean) * rs * g.y + bb.y;
        v.z = (a[i].z - mean) * rs * g.z + bb.z;
        v.w = (a[i].w - mean) * rs * g.w + bb.w;
        xp[lane + i * 64] = v;
        ushort4 u; u.x = f2bfu(v.x); u.y = f2bfu(v.y); u.z = f2bfu(v.z); u.w = f2bfu(v.w);
        *(ushort4*)(xb + (size_t)row * D_ + lane * 4 + i * 256) = u;
    }
}

// ---------------- global-token index extraction ----------------
__global__ __launch_bounds__(256) void k_idx(const int* __restrict__ ids, int* __restrict__ idxg) {
    int b = blockIdx.x;
    int t = threadIdx.x;
    __shared__ int cnt[256];
    __shared__ int totsh;
    int loc[16];
    int n = 0;
#pragma unroll
    for (int i = 0; i < 16; i++) {
        int s = t * 16 + i;
        if (s == 0 || ids[b * S_ + s] == SEP_) loc[n++] = s;
    }
    cnt[t] = n;
    __syncthreads();
    int base = 0;
    for (int u = 0; u < t; u++) base += cnt[u];
    for (int i = 0; i < n; i++) {
        int o = base + i;
        if (o < G_) idxg[b * G_ + o] = loc[i];
    }
    if (t == 255) totsh = base + n;
    __syncthreads();
    if (t == 0)
        for (int o = totsh; o < G_; o++) idxg[b * G_ + o] = 0;
}

// ---------------- legacy 128^2 MFMA GEMM (fallback path, Wf f32 support) ----------------
__global__ __launch_bounds__(256) void k_gemm_mfma(
    const unsigned short* __restrict__ A, const unsigned short* __restrict__ Wt,
    const float* __restrict__ Wf, const float* __restrict__ bias,
    float* __restrict__ Cf, float* __restrict__ Cf2, unsigned short* __restrict__ Cb,
    int M, int N, int K, int act) {
    __shared__ __align__(16) unsigned short As[2 * 128 * 32];
    __shared__ __align__(16) unsigned short Bs[2 * 128 * 32];
    int bx = blockIdx.x, by = blockIdx.y, bz = blockIdx.z;
    xcd_remap(bx, by, bz);
    int t = threadIdx.x;
    int wave = t >> 6, lane = t & 63, l16 = lane & 15, quad = lane >> 4;
    int m0 = by << 7, n0 = bx << 7;
    int wm = (wave >> 1) << 6, wn = (wave & 1) << 6;
    int slice = bz;
    int kper = K / gridDim.z;
    int kbeg = slice * kper, kend = kbeg + kper;
    f32x4 acc[4][4];
#pragma unroll
    for (int i = 0; i < 4; i++)
#pragma unroll
        for (int j = 0; j < 4; j++) acc[i][j] = (f32x4){0.f, 0.f, 0.f, 0.f};

    int ch = wave * 128 + lane;
    int srow = ch >> 2, spos = ch & 3;
    const unsigned short* ag = A + (size_t)(m0 + srow) * K + kbeg + spos * 8;

    if (Wt) {
        const unsigned short* bg = Wt + (size_t)(n0 + srow) * K + kbeg + spos * 8;
        gl16(ag, As + wave * 1024);
        gl16(ag + (size_t)16 * K, As + wave * 1024 + 512);
        gl16(bg, Bs + wave * 1024);
        gl16(bg + (size_t)16 * K, Bs + wave * 1024 + 512);
        WAIT_VM0_BARRIER();
        int cur = 0;
        for (int k0 = kbeg; k0 < kend; k0 += 32) {
            int koff = k0 + 32 - kbeg;
            if (k0 + 32 < kend) {
                int nb = cur ^ 1;
                gl16(ag + koff, As + nb * 4096 + wave * 1024);
                gl16(ag + koff + (size_t)16 * K, As + nb * 4096 + wave * 1024 + 512);
                gl16(bg + koff, Bs + nb * 4096 + wave * 1024);
                gl16(bg + koff + (size_t)16 * K, Bs + nb * 4096 + wave * 1024 + 512);
            }
            const unsigned short* Ab = As + cur * 4096;
            const unsigned short* Bb = Bs + cur * 4096;
            GEMM_COMPUTE(Ab, Bb);
            WAIT_VM0_BARRIER();
            cur ^= 1;
        }
    } else {
        int bn = t & 127, bkh = (t >> 7) << 4;
        for (int k0 = kbeg; k0 < kend; k0 += 32) {
            gl16(ag + (k0 - kbeg), As + wave * 1024);
            gl16(ag + (k0 - kbeg) + (size_t)16 * K, As + wave * 1024 + 512);
            const float* bp = Wf + (size_t)(k0 + bkh) * N + n0 + bn;
            unsigned int pk[8];
#pragma unroll
            for (int i = 0; i < 8; i++) {
                unsigned int lo = f2bfu(bp[(size_t)(2 * i) * N]);
                unsigned int hi = f2bfu(bp[(size_t)(2 * i + 1) * N]);
                pk[i] = lo | (hi << 16);
            }
            *(uint4*)&Bs[bn * 32 + bkh] = *(uint4*)&pk[0];
            *(uint4*)&Bs[bn * 32 + bkh + 8] = *(uint4*)&pk[4];
            __syncthreads();
            GEMM_COMPUTE(As, Bs);
            __syncthreads();
        }
    }
    float bj[4];
#pragma unroll
    for (int j = 0; j < 4; j++) bj[j] = (slice == 0) ? bias[n0 + wn + j * 16 + l16] : 0.f;
    float* outp = (slice == 0) ? Cf : Cf2;
#pragma unroll
    for (int i = 0; i < 4; i++)
#pragma unroll
        for (int j = 0; j < 4; j++) {
            int col = n0 + wn + j * 16 + l16;
#pragma unroll
            for (int r = 0; r < 4; r++) {
                int row = m0 + wm + i * 16 + quad * 4 + r;
                float v = acc[i][j][r] + bj[j];
                if (act) v = gelu_tanh(v);
                if (outp) outp[(size_t)row * N + col] = v;
                else      Cb[(size_t)row * N + col] = f2bfu(v);
            }
        }
}

// ---------------- legacy fused 5-way projection GEMM (fallback path) ----------------
__global__ __launch_bounds__(256) void k_gemm_qkv5(
    const unsigned short* __restrict__ A, P5 p) {
    __shared__ __align__(16) unsigned short As[2 * 128 * 32];
    __shared__ __align__(16) unsigned short Bs[2 * 128 * 32];
    int bx = blockIdx.x, by = blockIdx.y, bz = blockIdx.z;
    xcd_remap(bx, by, bz);
    const unsigned short* __restrict__ Wt = p.Wt[bz];
    const float* __restrict__ Wf = p.Wf[bz];
    const float* __restrict__ bias = p.bias[bz];
    unsigned short* __restrict__ Cb = p.out[bz];
    const int N = D_, K = D_;
    int t = threadIdx.x;
    int wave = t >> 6, lane = t & 63, l16 = lane & 15, quad = lane >> 4;
    int m0 = by << 7, n0 = bx << 7;
    int wm = (wave >> 1) << 6, wn = (wave & 1) << 6;
    f32x4 acc[4][4];
#pragma unroll
    for (int i = 0; i < 4; i++)
#pragma unroll
        for (int j = 0; j < 4; j++) acc[i][j] = (f32x4){0.f, 0.f, 0.f, 0.f};

    int ch = wave * 128 + lane;
    int srow = ch >> 2, spos = ch & 3;
    const unsigned short* ag = A + (size_t)(m0 + srow) * K + spos * 8;

    if (Wt) {
        const unsigned short* bg = Wt + (size_t)(n0 + srow) * K + spos * 8;
        gl16(ag, As + wave * 1024);
        gl16(ag + (size_t)16 * K, As + wave * 1024 + 512);
        gl16(bg, Bs + wave * 1024);
        gl16(bg + (size_t)16 * K, Bs + wave * 1024 + 512);
        WAIT_VM0_BARRIER();
        int cur = 0;
        for (int k0 = 0; k0 < K; k0 += 32) {
            int koff = k0 + 32;
            if (koff < K) {
                int nb = cur ^ 1;
                gl16(ag + koff, As + nb * 4096 + wave * 1024);
                gl16(ag + koff + (size_t)16 * K, As + nb * 4096 + wave * 1024 + 512);
                gl16(bg + koff, Bs + nb * 4096 + wave * 1024);
                gl16(bg + koff + (size_t)16 * K, Bs + nb * 4096 + wave * 1024 + 512);
            }
            const unsigned short* Ab = As + cur * 4096;
            const unsigned short* Bb = Bs + cur * 4096;
            GEMM_COMPUTE(Ab, Bb);
            WAIT_VM0_BARRIER();
            cur ^= 1;
        }
    } else {
        int bn = t & 127, bkh = (t >> 7) << 4;
        for (int k0 = 0; k0 < K; k0 += 32) {
            gl16(ag + k0, As + wave * 1024);
            gl16(ag + k0 + (size_t)16 * K, As + wave * 1024 + 512);
            const float* bp = Wf + (size_t)(k0 + bkh) * N + n0 + bn;
            unsigned int pk[8];
#pragma unroll
            for (int i = 0; i < 8; i++) {
                unsigned int lo = f2bfu(bp[(size_t)(2 * i) * N]);
                unsigned int hi = f2bfu(bp[(size_t)(2 * i + 1) * N]);
                pk[i] = lo | (hi << 16);
            }
            *(uint4*)&Bs[bn * 32 + bkh] = *(uint4*)&pk[0];
            *(uint4*)&Bs[bn * 32 + bkh + 8] = *(uint4*)&pk[4];
            __syncthreads();
            GEMM_COMPUTE(As, Bs);
            __syncthreads();
        }
    }
    float bj[4];
#pragma unroll
    for (int j = 0; j < 4; j++) bj[j] = bias[n0 + wn + j * 16 + l16];
#pragma unroll
    for (int i = 0; i < 4; i++)
#pragma unroll
        for (int j = 0; j < 4; j++) {
            int col = n0 + wn + j * 16 + l16;
#pragma unroll
            for (int r = 0; r < 4; r++) {
                int row = m0 + wm + i * 16 + quad * 4 + r;
                float v = acc[i][j][r] + bj[j];
                size_t adr = ((((size_t)(row >> 12)) * H_ + (col >> 6)) * S_ +
                              (row & (S_ - 1))) * DH_ + (col & 63);
                Cb[adr] = f2bfu(v);
            }
        }
}

// ---------------- MFMA flash local attention ----------------
// 128 q-rows/block (4 waves x 32 rows, 2 q-subtiles/wave), dbuf K/V, 1 barrier/tile,
// XCD-banded block mapping (each XCD owns 4 consecutive s0 blocks per (h,b)).
__global__ __launch_bounds__(256) void k_lattn(
    const unsigned short* __restrict__ q, const unsigned short* __restrict__ k,
    const unsigned short* __restrict__ v, const int* __restrict__ ids,
    const int* __restrict__ am, const int* __restrict__ idxg,
    unsigned short* __restrict__ Tb) {
    // bijective XCD-band decode: grid (32, H, B) = 768 = 8 XCD x 96
    int flat = blockIdx.x + 32 * (blockIdx.y + H_ * blockIdx.z);
    int xcd = flat & 7, idx = flat >> 3;
    int i4 = idx & 3, hb = idx >> 2;
    int bx = (xcd << 2) + i4;
    int h = hb % H_, b = hb / H_;
    int s0 = bx << 7;
    int t = threadIdx.x;
    int wave = t >> 6, lane = t & 63, l16 = lane & 15, quad = lane >> 4;

    __shared__ unsigned short Ks[2][64][72];
    __shared__ unsigned short Vt[2][64][72];   // swizzled d-major V tiles
    __shared__ unsigned short Ps[64][72];      // wave-private 16-row stripes (reused per subtile)
    __shared__ unsigned char keyok[2][64];

    const size_t headbase = (((size_t)b * H_) + h) * S_;
    short8 qa[2][2];
#pragma unroll
    for (int qs = 0; qs < 2; qs++) {
        int qrow = s0 + wave * 32 + qs * 16 + l16;
        const unsigned short* qptr = q + (headbase + qrow) * DH_;
        qa[qs][0] = *(const short8*)(qptr + quad * 8);
        qa[qs][1] = *(const short8*)(qptr + 32 + quad * 8);
    }

    f32x4 O[2][4];
    float m_run[2][4], l_run[2][4];
#pragma unroll
    for (int qs = 0; qs < 2; qs++)
#pragma unroll
        for (int nf = 0; nf < 4; nf++) {
            O[qs][nf] = (f32x4){0.f, 0.f, 0.f, 0.f};
            m_run[qs][nf] = -3.4e38f; l_run[qs][nf] = 0.f;
        }

    int kbase = s0 - 256;
    int sr = t >> 2, sc = t & 3;
    uint4 k0v, k1v, v0v, v1v; bool okf = false;

    auto FETCH = [&](int tile) {
        int sK, sclamp;
        if (tile < 10) {
            sK = kbase + tile * 64 + sr;
            bool inr = (sK >= 0) && (sK < S_);
            sclamp = inr ? sK : 0;
            okf = inr && (am[b * S_ + sclamp] != 0) &&
                  !((ids[b * S_ + sclamp] == SEP_) || (sK == 0));
        } else {
            sclamp = idxg[b * G_ + sr];
            okf = true;
        }
        const unsigned short* srcK = k + (headbase + sclamp) * DH_;
        const unsigned short* srcV = v + (headbase + sclamp) * DH_;
        k0v = *(const uint4*)(srcK + sc * 8);
        k1v = *(const uint4*)(srcK + (sc + 4) * 8);
        v0v = *(const uint4*)(srcV + sc * 8);
        v1v = *(const uint4*)(srcV + (sc + 4) * 8);
    };
    auto WRITE = [&](int buf) {
        if (sc == 0) keyok[buf][sr] = okf ? 1 : 0;
        *(uint4*)&Ks[buf][sr][sc * 8] = k0v;
        *(uint4*)&Ks[buf][sr][(sc + 4) * 8] = k1v;
        STAGE_V_SWZ(Vt[buf], v0v, v1v, sr, sc);
    };

    FETCH(0); WRITE(0);
    __syncthreads();

    for (int tile = 0; tile < 11; tile++) {
        int cur = tile & 1;
        if (tile < 10) FETCH(tile + 1);   // next-tile loads hidden under 2-subtile compute

        int ktb = kbase + tile * 64;
        bool kval[4];
#pragma unroll
        for (int nf = 0; nf < 4; nf++)
            kval[nf] = (tile == 10) || (keyok[cur][nf * 16 + l16] != 0);

#pragma unroll
        for (int qs = 0; qs < 2; qs++) {
            f32x4 Sf[4];
#pragma unroll
            for (int nf = 0; nf < 4; nf++) {
                short8 b0 = *(const short8*)&Ks[cur][nf * 16 + l16][quad * 8];
                short8 b1 = *(const short8*)&Ks[cur][nf * 16 + l16][32 + quad * 8];
                f32x4 a = (f32x4){0.f, 0.f, 0.f, 0.f};
                a = __builtin_amdgcn_mfma_f32_16x16x32_bf16(qa[qs][0], b0, a, 0, 0, 0);
                a = __builtin_amdgcn_mfma_f32_16x16x32_bf16(qa[qs][1], b1, a, 0, 0, 0);
                Sf[nf] = a;
            }
            float P_[4][4];
            float mt[4];
#pragma unroll
            for (int r = 0; r < 4; r++) {
                int qrc = s0 + wave * 32 + qs * 16 + quad * 4 + r;
                float mx = -3.4e38f;
#pragma unroll
                for (int nf = 0; nf < 4; nf++) {
                    int ks2 = ktb + nf * 16 + l16;
                    bool ok = kval[nf] && ((tile == 10) || (ks2 >= qrc - 256 && ks2 <= qrc + 256));
                    float sv = ok ? Sf[nf][r] * 0.125f : NEG_;
                    P_[nf][r] = sv;
                    mx = fmaxf(mx, sv);
                }
                mt[r] = mx;
            }
#pragma unroll
            for (int off = 1; off < 16; off <<= 1)
#pragma unroll
                for (int r = 0; r < 4; r++) mt[r] = fmaxf(mt[r], __shfl_xor(mt[r], off));
            float alpha[4], lt[4];
#pragma unroll
            for (int r = 0; r < 4; r++) {
                float mn = fmaxf(m_run[qs][r], mt[r]);
                alpha[r] = __expf(m_run[qs][r] - mn);
                m_run[qs][r] = mn; lt[r] = 0.f;
            }
#pragma unroll
            for (int nf = 0; nf < 4; nf++)
#pragma unroll
                for (int r = 0; r < 4; r++) {
                    float p = (P_[nf][r] > -1.0e8f) ? __expf(P_[nf][r] - m_run[qs][r]) : 0.f;
                    P_[nf][r] = p; lt[r] += p;
                }
#pragma unroll
            for (int off = 1; off < 16; off <<= 1)
#pragma unroll
                for (int r = 0; r < 4; r++) lt[r] += __shfl_xor(lt[r], off);
#pragma unroll
            for (int r = 0; r < 4; r++) l_run[qs][r] = l_run[qs][r] * alpha[r] + lt[r];
#pragma unroll
            for (int nf = 0; nf < 4; nf++) {
                O[qs][nf][0] *= alpha[0]; O[qs][nf][1] *= alpha[1];
                O[qs][nf][2] *= alpha[2]; O[qs][nf][3] *= alpha[3];
            }
#pragma unroll
            for (int nf = 0; nf < 4; nf++)
#pragma unroll
                for (int r = 0; r < 4; r++)
                    Ps[wave * 16 + quad * 4 + r][nf * 16 + l16] = f2bfu(P_[nf][r]);
            // wave-private stripe: ds_write -> ds_read ordering within wave handled by compiler
#pragma unroll
            for (int hh = 0; hh < 2; hh++) {
                short8 pa = *(const short8*)&Ps[wave * 16 + l16][hh * 32 + quad * 8];
#pragma unroll
                for (int nf = 0; nf < 4; nf++) {
                    short8 vb8 = READ_V_SWZ(Vt[cur], nf * 16 + l16, hh);
                    O[qs][nf] = __builtin_amdgcn_mfma_f32_16x16x32_bf16(pa, vb8, O[qs][nf], 0, 0, 0);
                }
            }
        }
        if (tile < 10) WRITE(cur ^ 1);    // write-after-read safe across the tile barrier
        __syncthreads();
    }
#pragma unroll
    for (int qs = 0; qs < 2; qs++)
#pragma unroll
        for (int r = 0; r < 4; r++) {
            int qrow = s0 + wave * 32 + qs * 16 + quad * 4 + r;
            float invl = 1.0f / l_run[qs][r];
            size_t base = ((size_t)(b * S_ + qrow)) * D_ + h * DH_;
#pragma unroll
            for (int nf = 0; nf < 4; nf++)
                Tb[base + nf * 16 + l16] = f2bfu(O[qs][nf][r] * invl);
        }
}

// ---------------- MFMA global-query attention, pass 1 (pipelined) ----------------
__global__ __launch_bounds__(256) void k_gattn_part(
    const unsigned short* __restrict__ qg, const unsigned short* __restrict__ kga,
    const unsigned short* __restrict__ vga, const int* __restrict__ am,
    float* __restrict__ Opart, float* __restrict__ mbuf, float* __restrict__ lbuf) {
    int c = blockIdx.x, h = blockIdx.y, b = blockIdx.z;
    int t = threadIdx.x;
    int wave = t >> 6, lane = t & 63, l16 = lane & 15, quad = lane >> 4;

    __shared__ unsigned short Ks[2][64][72];
    __shared__ unsigned short Vt[2][64][72];
    __shared__ unsigned short Ps[64][72];
    __shared__ unsigned char keyok[2][64];

    const size_t headbase = (((size_t)b * H_) + h) * S_;
    int grow = wave * 16 + l16;
    const unsigned short* qptr = qg + ((size_t)(b * G_ + grow)) * D_ + h * DH_;
    short8 qa0 = *(const short8*)(qptr + quad * 8);
    short8 qa1 = *(const short8*)(qptr + 32 + quad * 8);

    f32x4 O[4];
#pragma unroll
    for (int nf = 0; nf < 4; nf++) O[nf] = (f32x4){0.f, 0.f, 0.f, 0.f};
    float m_run[4] = {-3.4e38f, -3.4e38f, -3.4e38f, -3.4e38f};
    float l_run[4] = {0.f, 0.f, 0.f, 0.f};

    int kbase = c * 256;
    int sr = t >> 2, sc = t & 3;

    uint4 k0v, k1v, v0v, v1v; bool okf = false;

    auto FETCH = [&](int tile) {
        int sK = kbase + tile * 64 + sr;
        okf = (am[b * S_ + sK] != 0);
        const unsigned short* srcK = kga + (headbase + sK) * DH_;
        const unsigned short* srcV = vga + (headbase + sK) * DH_;
        k0v = *(const uint4*)(srcK + sc * 8);
        k1v = *(const uint4*)(srcK + (sc + 4) * 8);
        v0v = *(const uint4*)(srcV + sc * 8);
        v1v = *(const uint4*)(srcV + (sc + 4) * 8);
    };
    auto WRITE = [&](int buf) {
        if (sc == 0) keyok[buf][sr] = okf ? 1 : 0;
        *(uint4*)&Ks[buf][sr][sc * 8] = k0v;
        *(uint4*)&Ks[buf][sr][(sc + 4) * 8] = k1v;
        STAGE_V_SWZ(Vt[buf], v0v, v1v, sr, sc);
    };

    FETCH(0); WRITE(0);
    __syncthreads();

    for (int tile = 0; tile < 4; tile++) {
        int cur = tile & 1;
        if (tile < 3) FETCH(tile + 1);

        f32x4 Sf[4];
#pragma unroll
        for (int nf = 0; nf < 4; nf++) {
            short8 b0 = *(const short8*)&Ks[cur][nf * 16 + l16][quad * 8];
            short8 b1 = *(const short8*)&Ks[cur][nf * 16 + l16][32 + quad * 8];
            f32x4 a = (f32x4){0.f, 0.f, 0.f, 0.f};
            a = __builtin_amdgcn_mfma_f32_16x16x32_bf16(qa0, b0, a, 0, 0, 0);
            a = __builtin_amdgcn_mfma_f32_16x16x32_bf16(qa1, b1, a, 0, 0, 0);
            Sf[nf] = a;
        }
        bool kval[4];
#pragma unroll
        for (int nf = 0; nf < 4; nf++) kval[nf] = (keyok[cur][nf * 16 + l16] != 0);
        float P_[4][4];
        float mt[4];
#pragma unroll
        for (int r = 0; r < 4; r++) {
            float mx = -3.4e38f;
#pragma unroll
            for (int nf = 0; nf < 4; nf++) {
                float sv = kval[nf] ? Sf[nf][r] * 0.125f : NEG_;
                P_[nf][r] = sv;
                mx = fmaxf(mx, sv);
            }
            mt[r] = mx;
        }
#pragma unroll
        for (int off = 1; off < 16; off <<= 1)
#pragma unroll
            for (int r = 0; r < 4; r++) mt[r] = fmaxf(mt[r], __shfl_xor(mt[r], off));
        float alpha[4], lt[4];
#pragma unroll
        for (int r = 0; r < 4; r++) {
            float mn = fmaxf(m_run[r], mt[r]);
            alpha[r] = __expf(m_run[r] - mn);
            m_run[r] = mn; lt[r] = 0.f;
        }
#pragma unroll
        for (int nf = 0; nf < 4; nf++)
#pragma unroll
            for (int r = 0; r < 4; r++) {
                float p = (P_[nf][r] > -1.0e8f) ? __expf(P_[nf][r] - m_run[r]) : 0.f;
                P_[nf][r] = p; lt[r] += p;
            }
#pragma unroll
        for (int off = 1; off < 16; off <<= 1)
#pragma unroll
            for (int r = 0; r < 4; r++) lt[r] += __shfl_xor(lt[r], off);
#pragma unroll
        for (int r = 0; r < 4; r++) l_run[r] = l_run[r] * alpha[r] + lt[r];
#pragma unroll
        for (int nf = 0; nf < 4; nf++) {
            O[nf][0] *= alpha[0]; O[nf][1] *= alpha[1];
            O[nf][2] *= alpha[2]; O[nf][3] *= alpha[3];
        }
#pragma unroll
        for (int nf = 0; nf < 4; nf++)
#pragma unroll
            for (int r = 0; r < 4; r++)
                Ps[wave * 16 + quad * 4 + r][nf * 16 + l16] = f2bfu(P_[nf][r]);
#pragma unroll
        for (int hh = 0; hh < 2; hh++) {
            short8 pa = *(const short8*)&Ps[wave * 16 + l16][hh * 32 + quad * 8];
#pragma unroll
            for (int nf = 0; nf < 4; nf++) {
                short8 vb8 = READ_V_SWZ(Vt[cur], nf * 16 + l16, hh);
                O[nf] = __builtin_amdgcn_mfma_f32_16x16x32_bf16(pa, vb8, O[nf], 0, 0, 0);
            }
        }
        if (tile < 3) WRITE(cur ^ 1);
        __syncthreads();
    }
    size_t bhc = ((size_t)(b * H_ + h)) * NC_ + c;
#pragma unroll
    for (int r = 0; r < 4; r++) {
        int row = wave * 16 + quad * 4 + r;
#pragma unroll
        for (int nf = 0; nf < 4; nf++)
            Opart[bhc * (G_ * DH_) + (size_t)row * DH_ + nf * 16 + l16] = O[nf][r];
        if (l16 == 0) {
            mbuf[bhc * G_ + row] = m_run[r];
            lbuf[bhc * G_ + row] = l_run[r];
        }
    }
}

// ---------------- global attention pass 2 ----------------
__global__ __launch_bounds__(64) void k_gattn_comb(
    const float* __restrict__ Opart, const float* __restrict__ mbuf,
    const float* __restrict__ lbuf, const int* __restrict__ idxg,
    unsigned short* __restrict__ Tb) {
    int g = blockIdx.x, h = blockIdx.y, b = blockIdx.z;
    int d = threadIdx.x;
    size_t bh = (size_t)(b * H_ + h);
    float M = -3.4e38f;
    float mv[NC_];
#pragma unroll
    for (int c = 0; c < NC_; c++) {
        mv[c] = mbuf[(bh * NC_ + c) * G_ + g];
        M = fmaxf(M, mv[c]);
    }
    float L = 0.f, o = 0.f;
#pragma unroll
    for (int c = 0; c < NC_; c++) {
        float e = __expf(mv[c] - M);
        L += lbuf[(bh * NC_ + c) * G_ + g] * e;
        o += Opart[(bh * NC_ + c) * (G_ * DH_) + (size_t)g * DH_ + d] * e;
    }
    int srow = idxg[b * G_ + g];
    Tb[((size_t)(b * S_ + srow)) * D_ + h * DH_ + d] = f2bfu(o / L);
}

// ---------------- VALU GEMM (small M); optional row gather via idxg from xsrc ----------------
__global__ __launch_bounds__(256) void k_gemm(
    const float* __restrict__ A, const float* __restrict__ Bw,
    const float* __restrict__ bias, float* __restrict__ Cf,
    unsigned short* __restrict__ Cb, int M, int N, int K, int act,
    const float* __restrict__ xsrc, const int* __restrict__ idxg) {
    __shared__ float As[16][68];
    __shared__ float Bs[16][68];
    int tl = threadIdx.x;
    int tx = tl & 15, ty = tl >> 4;
    int m0 = blockIdx.y << 6, n0 = blockIdx.x << 6;
    float c[4][4] = {{0.f}};
    int arow = tl >> 2, akk = (tl & 3) << 2;
    int bkk = tl >> 4, bcol = (tl & 15) << 2;
    const float* arow_p;
    if (idxg) {
        int bg = m0 + arow;
        int bb = bg >> 6;                 // G_ = 64
        int srow = idxg[bg];
        arow_p = xsrc + ((size_t)(bb * S_ + srow)) * D_;
    } else {
        arow_p = A + (size_t)(m0 + arow) * K;
    }
    for (int k0 = 0; k0 < K; k0 += 16) {
        float4 a4 = *(const float4*)(arow_p + k0 + akk);
        As[akk + 0][arow] = a4.x; As[akk + 1][arow] = a4.y;
        As[akk + 2][arow] = a4.z; As[akk + 3][arow] = a4.w;
        float4 b4 = *(const float4*)(Bw + (size_t)(k0 + bkk) * N + n0 + bcol);
        Bs[bkk][bcol + 0] = b4.x; Bs[bkk][bcol + 1] = b4.y;
        Bs[bkk][bcol + 2] = b4.z; Bs[bkk][bcol + 3] = b4.w;
        __syncthreads();
#pragma unroll
        for (int kk = 0; kk < 16; kk++) {
            float4 av = *(const float4*)&As[kk][ty << 2];
            float4 bv = *(const float4*)&Bs[kk][tx << 2];
            float aa[4] = {av.x, av.y, av.z, av.w};
            float bb[4] = {bv.x, bv.y, bv.z, bv.w};
#pragma unroll
            for (int i = 0; i < 4; i++)
#pragma unroll
                for (int j = 0; j < 4; j++) c[i][j] += aa[i] * bb[j];
        }
        __syncthreads();
    }
    float bias4[4];
#pragma unroll
    for (int j = 0; j < 4; j++) bias4[j] = bias[n0 + (tx << 2) + j];
#pragma unroll
    for (int i = 0; i < 4; i++) {
        int mrow = m0 + (ty << 2) + i;
        float v0 = c[i][0] + bias4[0], v1 = c[i][1] + bias4[1];
        float v2 = c[i][2] + bias4[2], v3 = c[i][3] + bias4[3];
        if (act) { v0 = gelu_tanh(v0); v1 = gelu_tanh(v1); v2 = gelu_tanh(v2); v3 = gelu_tanh(v3); }
        if (Cf) {
            float4 o; o.x = v0; o.y = v1; o.z = v2; o.w = v3;
            *(float4*)(Cf + (size_t)mrow * N + n0 + (tx << 2)) = o;
        } else {
            ushort4 o; o.x = f2bfu(v0); o.y = f2bfu(v1); o.z = f2bfu(v2); o.w = f2bfu(v3);
            *(ushort4*)(Cb + (size_t)mrow * N + n0 + (tx << 2)) = o;
        }
    }
}

// ---------------- classifier ----------------
__global__ __launch_bounds__(256) void k_classifier(
    const float* __restrict__ x, const float* __restrict__ Wc,
    const float* __restrict__ bc, const int* __restrict__ lo_p,
    int rows_pb, float* __restrict__ out) {
    int r = blockIdx.x;
    int b = r / rows_pb, i = r % rows_pb;
    int s = lo_p[0] + i;
    int t = threadIdx.x;
    __shared__ float xr[D_];
    __shared__ float red[256];
    const float* xrow = x + ((size_t)(b * S_ + s)) * D_;
    for (int d = t; d < D_; d += 256) xr[d] = xrow[d];
    __syncthreads();
    for (int c = 0; c < C_; c++) {
        float loc = 0.f;
        for (int d = t; d < D_; d += 256) loc += xr[d] * Wc[d * C_ + c];
        red[t] = loc; __syncthreads();
        for (int o = 128; o; o >>= 1) { if (t < o) red[t] += red[t + o]; __syncthreads(); }
        if (t == 0) out[r * C_ + c] = red[0] + bc[c];
        __syncthreads();
    }
}

extern "C" void kernel_launch(void* const* d_in, const int* in_sizes, int n_in,
                              void* d_out, int out_size, void* d_ws, size_t ws_size,
                              hipStream_t stream) {
    (void)in_sizes; (void)n_in;
    const float* emb_tok = (const float*)d_in[0];
    const float* emb_pos = (const float*)d_in[1];
    const float* ln_e_s = (const float*)d_in[2];
    const float* ln_e_b = (const float*)d_in[3];
    const float* Wq  = (const float*)d_in[4];
    const float* bq  = (const float*)d_in[5];
    const float* Wk  = (const float*)d_in[6];
    const float* bk  = (const float*)d_in[7];
    const float* Wv  = (const float*)d_in[8];
    const float* bv  = (const float*)d_in[9];
    const float* Wqg = (const float*)d_in[10];
    const float* bqg = (const float*)d_in[11];
    const float* Wkg = (const float*)d_in[12];
    const float* bkg = (const float*)d_in[13];
    const float* Wvg = (const float*)d_in[14];
    const float* bvg = (const float*)d_in[15];
    const float* Wo  = (const float*)d_in[16];
    const float* bo  = (const float*)d_in[17];
    const float* ln1_s = (const float*)d_in[18];
    const float* ln1_b = (const float*)d_in[19];
    const float* Wf1 = (const float*)d_in[20];
    const float* bf1 = (const float*)d_in[21];
    const float* Wf2 = (const float*)d_in[22];
    const float* bf2 = (const float*)d_in[23];
    const float* ln2_s = (const float*)d_in[24];
    const float* ln2_b = (const float*)d_in[25];
    const float* Wc  = (const float*)d_in[26];
    const float* bc  = (const float*)d_in[27];
    const int* input_ids = (const int*)d_in[28];
    const int* attn_mask = (const int*)d_in[29];
    const int* lo        = (const int*)d_in[30];

    const size_t SZB = (size_t)B_ * S_ * D_;
    const size_t D2 = (size_t)D_ * D_;
    const size_t PL = 6 * D2 + 2 * (size_t)D_ * FF_;   // bf16 weight elems per layer
    uint8_t* w = (uint8_t*)d_ws;
    float*          x    = (float*)w;
    unsigned short* xb   = (unsigned short*)(w + 4 * SZB);
    float*          P    = (float*)(w + 6 * SZB);
    unsigned short* qb   = (unsigned short*)(w + 10 * SZB);
    unsigned short* kb   = (unsigned short*)(w + 12 * SZB);
    unsigned short* vb   = (unsigned short*)(w + 14 * SZB);
    unsigned short* kgab = (unsigned short*)(w + 16 * SZB);
    unsigned short* vgab = (unsigned short*)(w + 18 * SZB);
    unsigned short* Hb   = (unsigned short*)(w + 10 * SZB);
    unsigned short* Tb   = (unsigned short*)(w + 20 * SZB);
    unsigned short* qgb = (unsigned short*)(w + 22 * SZB + (size_t)B_ * G_ * D_ * 4);
    int* idxg = (int*)(w + 22 * SZB + (size_t)B_ * G_ * D_ * 4 + (size_t)B_ * G_ * D_ * 2);
    float* Opart = (float*)(w + 23 * SZB);
    float* mbuf  = (float*)(w + 24 * SZB);
    float* lbuf  = mbuf + (size_t)B_ * H_ * NC_ * G_;

    const size_t P2_OFF = 24 * SZB + (1u << 20);
    const size_t WB_OFF = P2_OFF + 4 * SZB;
    const size_t NEED_P2 = WB_OFF;
    const size_t NEED_W = WB_OFF + L_ * PL * 2;
    float* P2 = (float*)(w + P2_OFF);
    unsigned short* wb = (unsigned short*)(w + WB_OFF);
    const int useW = (ws_size >= NEED_W) ? 1 : 0;
    const int useSplit = (ws_size >= NEED_P2) ? 1 : 0;

    const int BS = B_ * S_;

    if (useW) {
        WT8 wt;
        int cum = 0;
        auto addop = [&](int opi, const float* s, unsigned short* d, int K, int N) {
            wt.src[opi] = s; wt.dst[opi] = d; wt.K[opi] = K; wt.N[opi] = N;
            wt.cum[opi] = cum; cum += L_ * (N / 32) * (K / 32);
        };
        addop(0, Wq,  wb + 0 * D2, D_, D_);
        addop(1, Wk,  wb + 1 * D2, D_, D_);
        addop(2, Wv,  wb + 2 * D2, D_, D_);
        addop(3, Wkg, wb + 3 * D2, D_, D_);
        addop(4, Wvg, wb + 4 * D2, D_, D_);
        addop(5, Wo,  wb + 5 * D2, D_, D_);
        addop(6, Wf1, wb + 6 * D2, D_, FF_);
        addop(7, Wf2, wb + 6 * D2 + (size_t)D_ * FF_, FF_, D_);
        wt.cum[8] = cum;
        k_wtrans_all<<<cum, 256, 0, stream>>>(wt, PL);
    }

    k_embed_ln<<<BS / 4, 256, 0, stream>>>(input_ids, emb_tok, emb_pos, ln_e_s, ln_e_b, x, xb);
    k_idx<<<B_, 256, 0, stream>>>(input_ids, idxg);

    dim3 g_ds(D_ / 128, BS / 128, useSplit ? 2 : 1);    // legacy split-K variant
    dim3 g_d5(D_ / 128, BS / 128, 5);
    dim3 g_ff(FF_ / 128, BS / 128);
    dim3 g_qg(D_ / 64, (B_ * G_) / 64);

    for (int l = 0; l < L_; l++) {
        const unsigned short* wbl = wb + (size_t)l * PL;
        P5 p5;
        p5.Wf[0] = Wq  + (size_t)l * D2;  p5.bias[0] = bq  + l * D_;  p5.out[0] = qb;
        p5.Wf[1] = Wk  + (size_t)l * D2;  p5.bias[1] = bk  + l * D_;  p5.out[1] = kb;
        p5.Wf[2] = Wv  + (size_t)l * D2;  p5.bias[2] = bv  + l * D_;  p5.out[2] = vb;
        p5.Wf[3] = Wkg + (size_t)l * D2;  p5.bias[3] = bkg + l * D_;  p5.out[3] = kgab;
        p5.Wf[4] = Wvg + (size_t)l * D2;  p5.bias[4] = bvg + l * D_;  p5.out[4] = vgab;
        for (int i = 0; i < 5; i++) p5.Wt[i] = useW ? (wbl + (size_t)i * D2) : nullptr;
        const float* Wqg_l = Wqg + (size_t)l * D2;
        const float* Wo_l  = Wo  + (size_t)l * D2;
        const float* Wf1_l = Wf1 + (size_t)l * D_ * FF_;
        const float* Wf2_l = Wf2 + (size_t)l * FF_ * D_;
        const unsigned short* Wo_t  = useW ? (wbl + 5 * D2) : nullptr;
        const unsigned short* Wf1_t = useW ? (wbl + 6 * D2) : nullptr;
        const unsigned short* Wf2_t = useW ? (wbl + 6 * D2 + (size_t)D_ * FF_) : nullptr;

        if (useW) {
            k_qkv5_256<<<dim3(D_ / 256, BS / 256, 5), 512, 0, stream>>>(xb, p5);
        } else {
            k_gemm_qkv5<<<g_d5, 256, 0, stream>>>(xb, p5);
        }
        k_lattn<<<dim3(S_ / 128, H_, B_), 256, 0, stream>>>(qb, kb, vb, input_ids, attn_mask, idxg, Tb);
        k_gemm<<<g_qg, 256, 0, stream>>>(nullptr, Wqg_l, bqg + l * D_, nullptr, qgb, B_ * G_, D_, D_, 0, x, idxg);
        k_gattn_part<<<dim3(NC_, H_, B_), 256, 0, stream>>>(qgb, kgab, vgab, attn_mask, Opart, mbuf, lbuf);
        k_gattn_comb<<<dim3(G_, H_, B_), 64, 0, stream>>>(Opart, mbuf, lbuf, idxg, Tb);
        if (useW) {
            k_gemm256_nt<<<dim3(D_ / 256, BS / 256, useSplit ? 2 : 1), 512, 0, stream>>>(
                Tb, Wo_t, bo + l * D_, P, P2, nullptr, BS, D_, D_, 0);
            k_add_ln<<<BS / 4, 256, 0, stream>>>(x, P, useSplit ? P2 : nullptr, ln1_s + l * D_, ln1_b + l * D_, xb);
            k_gemm256_nt<<<dim3(FF_ / 256, BS / 256, 1), 512, 0, stream>>>(
                xb, Wf1_t, bf1 + l * FF_, nullptr, nullptr, Hb, BS, FF_, D_, 1);
            k_gemm256_nt<<<dim3(D_ / 256, BS / 256, useSplit ? 2 : 1), 512, 0, stream>>>(
                Hb, Wf2_t, bf2 + l * D_, P, P2, nullptr, BS, D_, FF_, 0);
            k_add_ln<<<BS / 4, 256, 0, stream>>>(x, P, useSplit ? P2 : nullptr, ln2_s + l * D_, ln2_b + l * D_, xb);
        } else {
            k_gemm_mfma<<<g_ds, 256, 0, stream>>>(Tb, Wo_t, Wo_l, bo + l * D_, P, P2, nullptr, BS, D_, D_, 0);
            k_add_ln<<<BS / 4, 256, 0, stream>>>(x, P, useSplit ? P2 : nullptr, ln1_s + l * D_, ln1_b + l * D_, xb);
            k_gemm_mfma<<<g_ff, 256, 0, stream>>>(xb, Wf1_t, Wf1_l, bf1 + l * FF_, nullptr, nullptr, Hb, BS, FF_, D_, 1);
            k_gemm_mfma<<<g_ds, 256, 0, stream>>>(Hb, Wf2_t, Wf2_l, bf2 + l * D_, P, P2, nullptr, BS, D_, FF_, 0);
            k_add_ln<<<BS / 4, 256, 0, stream>>>(x, P, useSplit ? P2 : nullptr, ln2_s + l * D_, ln2_b + l * D_, xb);
        }
    }

    int rows = out_size / C_;
    int rows_pb = rows / B_;
    k_classifier<<<rows, 256, 0, stream>>>(x, Wc, bc, lo, rows_pb, (float*)d_out);
}

// Round 8
// 1056.600 us; speedup vs baseline: 1.0707x; 1.0707x over previous
//
#include <hip/hip_runtime.h>
#include <hip/hip_bf16.h>
#include <stdint.h>

#define B_ 2
#define S_ 4096
#define D_ 768
#define H_ 12
#define DH_ 64
#define L_ 2
#define W_ 256
#define G_ 64
#define FF_ 3072
#define C_ 7
#define SEP_ 2
#define NEG_ (-1000000000.0f)
#define NC_ 16

typedef __attribute__((ext_vector_type(8))) short short8;
typedef __attribute__((ext_vector_type(4))) float f32x4;

__device__ __forceinline__ float bfu2f(unsigned short u) {
    return __uint_as_float(((unsigned int)u) << 16);
}
__device__ __forceinline__ unsigned short f2bfu(float f) {
    unsigned int x = __float_as_uint(f);
    unsigned int r = (x + 0x7fffu + ((x >> 16) & 1u)) >> 16;
    return (unsigned short)r;
}
// gelu(tanh approx): 0.5*v*(1+tanh(c)) == v * sigmoid(2c)  (exact identity)
__device__ __forceinline__ float gelu_tanh(float v) {
    float u = 1.5957691216057308f * v + 0.0713548162726f * v * v * v;
    return v / (1.0f + __expf(-u));
}

// async global->LDS, 16B per lane. LDS dest must be wave-uniform base (HW adds lane*16).
__device__ __forceinline__ void gl16(const unsigned short* g, unsigned short* l) {
    __builtin_amdgcn_global_load_lds(
        (const __attribute__((address_space(1))) unsigned int*)g,
        (__attribute__((address_space(3))) unsigned int*)l,
        16, 0, 0);
}

// XCD-banded block remap (bijective; requires ny%8==0, true for all launches here).
__device__ __forceinline__ void xcd_remap(int& bx, int& by, int& bz) {
    int nx = gridDim.x, ny = gridDim.y, nz = gridDim.z;
    int flat = bx + nx * (by + ny * bz);
    int nxz = nx * nz;
    int xcd = flat & 7;
    int n = flat >> 3;
    int band = n / nxz;
    int r = n - band * nxz;
    by = xcd * (ny >> 3) + band;
    bz = r / nx;
    bx = r - bz * nx;
}

// ===== V staging into k-block-swizzled d-major LDS tile =====
// Layout: element (d, k) of a 64x64 V tile lives at Vt[d][ ((k>>3) ^ ((d>>3)&7))*8 + (k&7) ].
#define STAGE_V_SWZ(Vt, v0v, v1v, sr, sc)                                              \
    {                                                                                  \
        unsigned me0[4] = {v0v.x, v0v.y, v0v.z, v0v.w};                                \
        unsigned me1[4] = {v1v.x, v1v.y, v1v.z, v1v.w};                                \
        unsigned pc0[4], pc1[4];                                                       \
        _Pragma("unroll")                                                              \
        for (int i_ = 0; i_ < 4; i_++) {                                               \
            pc0[i_] = __shfl_xor(me0[i_], 4);                                          \
            pc1[i_] = __shfl_xor(me1[i_], 4);                                          \
        }                                                                              \
        int odd_ = (sr) & 1;                                                           \
        int scp_ = odd_ ? (sc) + 4 : (sc);                                             \
        int dbase_ = scp_ << 3;                                                        \
        int kcol_ = (((sr) >> 3) ^ scp_) << 3;                                         \
        int koff_ = kcol_ + ((sr) & 6);                                                \
        _Pragma("unroll")                                                              \
        for (int i_ = 0; i_ < 4; i_++) {                                               \
            unsigned lo_ = odd_ ? pc1[i_] : me0[i_];                                   \
            unsigned hi_ = odd_ ? me1[i_] : pc0[i_];                                   \
            unsigned w0_ = (lo_ & 0xffffu) | (hi_ << 16);                              \
            unsigned w1_ = (lo_ >> 16) | (hi_ & 0xffff0000u);                          \
            *(unsigned*)&Vt[dbase_ + 2 * i_][koff_] = w0_;                             \
            *(unsigned*)&Vt[dbase_ + 2 * i_ + 1][koff_] = w1_;                         \
        }                                                                              \
    }

// read the PV B-fragment (8 k-slots for column d=row) from the swizzled tile
#define READ_V_SWZ(Vt, row, hh)                                                        \
    (*(const short8*)&Vt[row][(((hh) * 4 + quad) ^ (((row) >> 3) & 7)) << 3])

// ================= 256x256 8-phase GEMM core (T2+T3+T4+T5 stack) =================
#define GEMM256_CORE(APTR, BTPTR, KVAL, KBEG, KPER)                                    \
    __shared__ __align__(16) unsigned short Lb[2 * 2 * 2 * 8192];                      \
    const int tid = threadIdx.x;                                                       \
    const int wave = tid >> 6, lane = tid & 63;                                        \
    const int l16 = lane & 15, quad = lane >> 4;                                       \
    const int wr = wave >> 2, wc = wave & 3;                                           \
    const int cw = (wc & 1) << 6;                                                      \
    const int srow = tid >> 3;                                                         \
    const int scol8 = (lane & 7) ^ ((lane >> 3) & 7);                                  \
    const int so0 = (quad ^ (l16 & 7)) << 3;                                           \
    const int so1 = so0 ^ 32;                                                          \
    f32x4 acc[8][4];                                                                   \
    _Pragma("unroll") for (int i_ = 0; i_ < 8; i_++)                                   \
        _Pragma("unroll") for (int j_ = 0; j_ < 4; j_++)                               \
            acc[i_][j_] = (f32x4){0.f, 0.f, 0.f, 0.f};                                 \
    auto stA = [&](int d, int h, int kofs) {                                           \
        const unsigned short* g = (APTR) +                                             \
            (size_t)(m0 + h * 128 + srow) * (KVAL) + kofs + scol8 * 8;                 \
        unsigned short* dst = Lb + (d * 4 + h) * 8192 + wave * 512;                    \
        gl16(g, dst);                                                                  \
        gl16(g + (size_t)64 * (KVAL), dst + 4096);                                     \
    };                                                                                 \
    auto stB = [&](int d, int h, int kofs) {                                           \
        const unsigned short* g = (BTPTR) +                                            \
            (size_t)(n0 + h * 128 + srow) * (KVAL) + kofs + scol8 * 8;                 \
        unsigned short* dst = Lb + (d * 4 + 2 + h) * 8192 + wave * 512;                \
        gl16(g, dst);                                                                  \
        gl16(g + (size_t)64 * (KVAL), dst + 4096);                                     \
    };                                                                                 \
    auto lda = [&](short8 av[4][2], int d, int mh) {                                   \
        const unsigned short* Ah = Lb + (d * 4 + wr) * 8192;                           \
        _Pragma("unroll") for (int fi = 0; fi < 4; fi++) {                             \
            int rl = mh * 64 + fi * 16 + l16;                                          \
            av[fi][0] = *(const short8*)(Ah + rl * 64 + so0);                          \
            av[fi][1] = *(const short8*)(Ah + rl * 64 + so1);                          \
        }                                                                              \
    };                                                                                 \
    auto ldb = [&](short8 bv[2][2], int d, int nh) {                                   \
        const unsigned short* Bh = Lb + (d * 4 + 2 + (wc >> 1)) * 8192;                \
        _Pragma("unroll") for (int j = 0; j < 2; j++) {                                \
            int rl = cw + nh * 32 + j * 16 + l16;                                      \
            bv[j][0] = *(const short8*)(Bh + rl * 64 + so0);                           \
            bv[j][1] = *(const short8*)(Bh + rl * 64 + so1);                           \
        }                                                                              \
    };                                                                                 \
    auto mm = [&](short8 av[4][2], short8 bv[2][2], int mh, int nh) {                  \
        _Pragma("unroll") for (int fi = 0; fi < 4; fi++)                               \
            _Pragma("unroll") for (int j = 0; j < 2; j++)                              \
                _Pragma("unroll") for (int kk = 0; kk < 2; kk++)                       \
                    acc[mh * 4 + fi][nh * 2 + j] =                                     \
                        __builtin_amdgcn_mfma_f32_16x16x32_bf16(                       \
                            av[fi][kk], bv[j][kk], acc[mh * 4 + fi][nh * 2 + j],       \
                            0, 0, 0);                                                  \
    };                                                                                 \
    stA(0, 0, (KBEG)); stA(0, 1, (KBEG)); stB(0, 0, (KBEG)); stB(0, 1, (KBEG));        \
    stB(1, 0, (KBEG) + 64); stB(1, 1, (KBEG) + 64);                                    \
    asm volatile("s_waitcnt vmcnt(4)" ::: "memory");                                   \
    __builtin_amdgcn_s_barrier();                                                      \
    {                                                                                  \
        const int NI = (KPER) >> 7;                                                    \
        short8 a[4][2], b0v[2][2], b1v[2][2];                                          \
        for (int it = 0; it < NI; it++) {                                              \
            int kof = (KBEG) + (it << 7);                                              \
            bool pre = (it + 1 < NI);                                                  \
            lda(a, 0, 0); ldb(b0v, 0, 0);                                              \
            stA(1, 0, kof + 64);                                                       \
            __builtin_amdgcn_s_barrier();                                              \
            __builtin_amdgcn_s_setprio(1); mm(a, b0v, 0, 0);                           \
            __builtin_amdgcn_s_setprio(0); __builtin_amdgcn_s_barrier();               \
            ldb(b1v, 0, 1); stA(1, 1, kof + 64);                                       \
            __builtin_amdgcn_s_barrier();                                              \
            __builtin_amdgcn_s_setprio(1); mm(a, b1v, 0, 1);                           \
            __builtin_amdgcn_s_setprio(0); __builtin_amdgcn_s_barrier();               \
            lda(a, 0, 1);                                                              \
            if (pre) stB(0, 0, kof + 128);                                             \
            __builtin_amdgcn_s_barrier();                                              \
            __builtin_amdgcn_s_setprio(1); mm(a, b1v, 1, 1);                           \
            __builtin_amdgcn_s_setprio(0); __builtin_amdgcn_s_barrier();               \
            if (pre) { stB(0, 1, kof + 128);                                           \
                       asm volatile("s_waitcnt vmcnt(4)" ::: "memory"); }              \
            else     { asm volatile("s_waitcnt vmcnt(0)" ::: "memory"); }              \
            __builtin_amdgcn_s_barrier();                                              \
            __builtin_amdgcn_s_setprio(1); mm(a, b0v, 1, 0);                           \
            __builtin_amdgcn_s_setprio(0); __builtin_amdgcn_s_barrier();               \
            lda(a, 1, 0); ldb(b0v, 1, 0);                                              \
            if (pre) stA(0, 0, kof + 128);                                             \
            __builtin_amdgcn_s_barrier();                                              \
            __builtin_amdgcn_s_setprio(1); mm(a, b0v, 0, 0);                           \
            __builtin_amdgcn_s_setprio(0); __builtin_amdgcn_s_barrier();               \
            ldb(b1v, 1, 1);                                                            \
            if (pre) stA(0, 1, kof + 128);                                             \
            __builtin_amdgcn_s_barrier();                                              \
            __builtin_amdgcn_s_setprio(1); mm(a, b1v, 0, 1);                           \
            __builtin_amdgcn_s_setprio(0); __builtin_amdgcn_s_barrier();               \
            lda(a, 1, 1);                                                              \
            if (pre) stB(1, 0, kof + 192);                                             \
            __builtin_amdgcn_s_barrier();                                              \
            __builtin_amdgcn_s_setprio(1); mm(a, b1v, 1, 1);                           \
            __builtin_amdgcn_s_setprio(0); __builtin_amdgcn_s_barrier();               \
            if (pre) { stB(1, 1, kof + 192);                                           \
                       asm volatile("s_waitcnt vmcnt(4)" ::: "memory"); }              \
            __builtin_amdgcn_s_barrier();                                              \
            __builtin_amdgcn_s_setprio(1); mm(a, b0v, 1, 0);                           \
            __builtin_amdgcn_s_setprio(0); __builtin_amdgcn_s_barrier();               \
        }                                                                              \
    }

// ---------------- 256^2 8-phase GEMM, generic epilogue ----------------
__global__ __launch_bounds__(512, 1) void k_gemm256_nt(
    const unsigned short* __restrict__ A, const unsigned short* __restrict__ Wt,
    const float* __restrict__ bias, float* __restrict__ Cf, float* __restrict__ Cf2,
    unsigned short* __restrict__ Cb, int M, int N, int K, int act) {
    int bx = blockIdx.x, by = blockIdx.y, bz = blockIdx.z;
    xcd_remap(bx, by, bz);
    int m0 = by << 8, n0 = bx << 8;
    int slice = bz;
    int kper = K / gridDim.z;
    int kbeg = slice * kper;
    GEMM256_CORE(A, Wt, K, kbeg, kper);
    float bj[4];
#pragma unroll
    for (int nj = 0; nj < 4; nj++)
        bj[nj] = (slice == 0) ? bias[n0 + (wc << 6) + nj * 16 + l16] : 0.f;
    float* outp = (slice == 0) ? Cf : Cf2;
#pragma unroll
    for (int mi = 0; mi < 8; mi++)
#pragma unroll
        for (int nj = 0; nj < 4; nj++) {
            int col = n0 + (wc << 6) + nj * 16 + l16;
#pragma unroll
            for (int rr = 0; rr < 4; rr++) {
                int row = m0 + (wr << 7) + mi * 16 + quad * 4 + rr;
                float v = acc[mi][nj][rr] + bj[nj];
                if (act) v = gelu_tanh(v);
                if (outp) outp[(size_t)row * N + col] = v;
                else      Cb[(size_t)row * N + col] = f2bfu(v);
            }
        }
}

// ---------------- 256^2 8-phase fused qkv5, head-major bf16 out ----------------
struct P5 {
    const unsigned short* Wt[5];
    const float* Wf[5];
    const float* bias[5];
    unsigned short* out[5];
};
__global__ __launch_bounds__(512, 1) void k_qkv5_256(
    const unsigned short* __restrict__ A, P5 p) {
    int bx = blockIdx.x, by = blockIdx.y, bz = blockIdx.z;
    xcd_remap(bx, by, bz);
    const unsigned short* __restrict__ Wt = p.Wt[bz];
    const float* __restrict__ bias = p.bias[bz];
    unsigned short* __restrict__ Cb = p.out[bz];
    const int K = D_;
    int m0 = by << 8, n0 = bx << 8;
    GEMM256_CORE(A, Wt, K, 0, K);
    float bj[4];
#pragma unroll
    for (int nj = 0; nj < 4; nj++) bj[nj] = bias[n0 + (wc << 6) + nj * 16 + l16];
#pragma unroll
    for (int mi = 0; mi < 8; mi++)
#pragma unroll
        for (int nj = 0; nj < 4; nj++) {
            int col = n0 + (wc << 6) + nj * 16 + l16;
#pragma unroll
            for (int rr = 0; rr < 4; rr++) {
                int row = m0 + (wr << 7) + mi * 16 + quad * 4 + rr;
                float v = acc[mi][nj][rr] + bj[nj];
                size_t adr = ((((size_t)(row >> 12)) * H_ + (col >> 6)) * S_ +
                              (row & (S_ - 1))) * DH_ + (col & 63);
                Cb[adr] = f2bfu(v);
            }
        }
}

// ---------------- legacy 128^2 helpers (fallback when no weight workspace) --------
#define GEMM_COMPUTE(Ab, Bb)                                                             \
    {                                                                                    \
        short8 af[4], bf[4];                                                             \
        _Pragma("unroll")                                                                \
        for (int i_ = 0; i_ < 4; i_++)                                                   \
            af[i_] = *(const short8*)&(Ab)[(wm + i_ * 16 + l16) * 32 + quad * 8];        \
        _Pragma("unroll")                                                                \
        for (int j_ = 0; j_ < 4; j_++)                                                   \
            bf[j_] = *(const short8*)&(Bb)[(wn + j_ * 16 + l16) * 32 + quad * 8];        \
        _Pragma("unroll")                                                                \
        for (int i_ = 0; i_ < 4; i_++)                                                   \
            _Pragma("unroll")                                                            \
            for (int j_ = 0; j_ < 4; j_++)                                               \
                acc[i_][j_] = __builtin_amdgcn_mfma_f32_16x16x32_bf16(af[i_], bf[j_],    \
                                                                      acc[i_][j_], 0, 0, 0); \
    }

#define WAIT_VM0_BARRIER()                                   \
    {                                                        \
        asm volatile("s_waitcnt vmcnt(0)" ::: "memory");     \
        __builtin_amdgcn_s_barrier();                        \
    }

// ---------------- merged weight convert+transpose (8 ops in one launch) ----------------
struct WT8 {
    const float* src[8];
    unsigned short* dst[8];
    int K[8], N[8];
    int cum[9];
};
__global__ __launch_bounds__(256) void k_wtrans_all(WT8 p, size_t PLs) {
    int blk = blockIdx.x;
    int op = 0;
#pragma unroll
    for (int i = 0; i < 7; i++) op += (blk >= p.cum[i + 1]) ? 1 : 0;
    int local = blk - p.cum[op];
    int K = p.K[op], N = p.N[op];
    int nx = N >> 5, ny = K >> 5;
    int l = local / (nx * ny);
    int rem = local - l * (nx * ny);
    int bxx = rem % nx, byy = rem / nx;
    const float* src = p.src[op] + (size_t)l * K * N;
    unsigned short* dst = p.dst[op] + (size_t)l * PLs;
    __shared__ unsigned short tile[32][36];
    int t = threadIdx.x;
    int r = t >> 3, c4 = (t & 7) << 2;
    int k0 = byy << 5, n0 = bxx << 5;
    float4 v = *(const float4*)(src + (size_t)(k0 + r) * N + n0 + c4);
    tile[c4 + 0][r] = f2bfu(v.x);
    tile[c4 + 1][r] = f2bfu(v.y);
    tile[c4 + 2][r] = f2bfu(v.z);
    tile[c4 + 3][r] = f2bfu(v.w);
    __syncthreads();
    ushort4 o;
    o.x = tile[r][c4 + 0]; o.y = tile[r][c4 + 1];
    o.z = tile[r][c4 + 2]; o.w = tile[r][c4 + 3];
    *(ushort4*)(dst + (size_t)(n0 + r) * K + k0 + c4) = o;
}

// ---------------- embedding + LN: one wave per row ----------------
__global__ __launch_bounds__(256) void k_embed_ln(
    const int* __restrict__ ids, const float* __restrict__ etok,
    const float* __restrict__ epos, const float* __restrict__ lns,
    const float* __restrict__ lnb, float* __restrict__ x,
    unsigned short* __restrict__ xb) {
    int row = (blockIdx.x << 2) + (threadIdx.x >> 6);
    int lane = threadIdx.x & 63;
    int s = row & (S_ - 1);
    int id = ids[row];
    const float4* ep = (const float4*)(etok + (size_t)id * D_);
    const float4* pp = (const float4*)(epos + (size_t)s * D_);
    float4 a[3];
    float sum = 0.f, sum2 = 0.f;
#pragma unroll
    for (int i = 0; i < 3; i++) {
        float4 ev = ep[lane + i * 64];
        float4 pv = pp[lane + i * 64];
        ev.x += pv.x; ev.y += pv.y; ev.z += pv.z; ev.w += pv.w;
        a[i] = ev;
        sum  += ev.x + ev.y + ev.z + ev.w;
        sum2 += ev.x * ev.x + ev.y * ev.y + ev.z * ev.z + ev.w * ev.w;
    }
#pragma unroll
    for (int off = 1; off < 64; off <<= 1) {
        sum += __shfl_xor(sum, off);
        sum2 += __shfl_xor(sum2, off);
    }
    float mean = sum * (1.0f / D_);
    float var = sum2 * (1.0f / D_) - mean * mean;
    float rs = rsqrtf(var + 1e-5f);
    float4* xp = (float4*)(x + (size_t)row * D_);
#pragma unroll
    for (int i = 0; i < 3; i++) {
        float4 g = *(const float4*)(lns + lane * 4 + i * 256);
        float4 bb = *(const float4*)(lnb + lane * 4 + i * 256);
        float4 v;
        v.x = (a[i].x - mean) * rs * g.x + bb.x;
        v.y = (a[i].y - mean) * rs * g.y + bb.y;
        v.z = (a[i].z - mean) * rs * g.z + bb.z;
        v.w = (a[i].w - mean) * rs * g.w + bb.w;
        xp[lane + i * 64] = v;
        ushort4 u; u.x = f2bfu(v.x); u.y = f2bfu(v.y); u.z = f2bfu(v.z); u.w = f2bfu(v.w);
        *(ushort4*)(xb + (size_t)row * D_ + lane * 4 + i * 256) = u;
    }
}

// ---------------- residual add + LN (x += y [+ y2]), one wave per row ----------------
__global__ __launch_bounds__(256) void k_add_ln(
    float* __restrict__ x, const float* __restrict__ y, const float* __restrict__ y2,
    const float* __restrict__ lns, const float* __restrict__ lnb,
    unsigned short* __restrict__ xb) {
    int row = (blockIdx.x << 2) + (threadIdx.x >> 6);
    int lane = threadIdx.x & 63;
    float4* xp = (float4*)(x + (size_t)row * D_);
    const float4* yp = (const float4*)(y + (size_t)row * D_);
    const float4* y2p = y2 ? (const float4*)(y2 + (size_t)row * D_) : nullptr;
    float4 a[3];
    float sum = 0.f, sum2 = 0.f;
#pragma unroll
    for (int i = 0; i < 3; i++) {
        float4 xv = xp[lane + i * 64];
        float4 yv = yp[lane + i * 64];
        xv.x += yv.x; xv.y += yv.y; xv.z += yv.z; xv.w += yv.w;
        if (y2p) {
            float4 zv = y2p[lane + i * 64];
            xv.x += zv.x; xv.y += zv.y; xv.z += zv.z; xv.w += zv.w;
        }
        a[i] = xv;
        sum  += xv.x + xv.y + xv.z + xv.w;
        sum2 += xv.x * xv.x + xv.y * xv.y + xv.z * xv.z + xv.w * xv.w;
    }
#pragma unroll
    for (int off = 1; off < 64; off <<= 1) {
        sum += __shfl_xor(sum, off);
        sum2 += __shfl_xor(sum2, off);
    }
    float mean = sum * (1.0f / D_);
    float var = sum2 * (1.0f / D_) - mean * mean;
    float rs = rsqrtf(var + 1e-5f);
#pragma unroll
    for (int i = 0; i < 3; i++) {
        float4 g = *(const float4*)(lns + lane * 4 + i * 256);
        float4 bb = *(const float4*)(lnb + lane * 4 + i * 256);
        float4 v;
        v.x = (a[i].x - mean) * rs * g.x + bb.x;
        v.y = (a[i].y - mean) * rs * g.y + bb.y;
        v.z = (a[i].z - mean) * rs * g.z + bb.z;
        v.w = (a[i].w - mean) * rs * g.w + bb.w;
        xp[lane + i * 64] = v;
        ushort4 u; u.x = f2bfu(v.x); u.y = f2bfu(v.y); u.z = f2bfu(v.z); u.w = f2bfu(v.w);
        *(ushort4*)(xb + (size_t)row * D_ + lane * 4 + i * 256) = u;
    }
}

// ---------------- global-token index extraction ----------------
__global__ __launch_bounds__(256) void k_idx(const int* __restrict__ ids, int* __restrict__ idxg) {
    int b = blockIdx.x;
    int t = threadIdx.x;
    __shared__ int cnt[256];
    __shared__ int totsh;
    int loc[16];
    int n = 0;
#pragma unroll
    for (int i = 0; i < 16; i++) {
        int s = t * 16 + i;
        if (s == 0 || ids[b * S_ + s] == SEP_) loc[n++] = s;
    }
    cnt[t] = n;
    __syncthreads();
    int base = 0;
    for (int u = 0; u < t; u++) base += cnt[u];
    for (int i = 0; i < n; i++) {
        int o = base + i;
        if (o < G_) idxg[b * G_ + o] = loc[i];
    }
    if (t == 255) totsh = base + n;
    __syncthreads();
    if (t == 0)
        for (int o = totsh; o < G_; o++) idxg[b * G_ + o] = 0;
}

// ---------------- legacy 128^2 MFMA GEMM (fallback path, Wf f32 support) ----------------
__global__ __launch_bounds__(256) void k_gemm_mfma(
    const unsigned short* __restrict__ A, const unsigned short* __restrict__ Wt,
    const float* __restrict__ Wf, const float* __restrict__ bias,
    float* __restrict__ Cf, float* __restrict__ Cf2, unsigned short* __restrict__ Cb,
    int M, int N, int K, int act) {
    __shared__ __align__(16) unsigned short As[2 * 128 * 32];
    __shared__ __align__(16) unsigned short Bs[2 * 128 * 32];
    int bx = blockIdx.x, by = blockIdx.y, bz = blockIdx.z;
    xcd_remap(bx, by, bz);
    int t = threadIdx.x;
    int wave = t >> 6, lane = t & 63, l16 = lane & 15, quad = lane >> 4;
    int m0 = by << 7, n0 = bx << 7;
    int wm = (wave >> 1) << 6, wn = (wave & 1) << 6;
    int slice = bz;
    int kper = K / gridDim.z;
    int kbeg = slice * kper, kend = kbeg + kper;
    f32x4 acc[4][4];
#pragma unroll
    for (int i = 0; i < 4; i++)
#pragma unroll
        for (int j = 0; j < 4; j++) acc[i][j] = (f32x4){0.f, 0.f, 0.f, 0.f};

    int ch = wave * 128 + lane;
    int srow = ch >> 2, spos = ch & 3;
    const unsigned short* ag = A + (size_t)(m0 + srow) * K + kbeg + spos * 8;

    if (Wt) {
        const unsigned short* bg = Wt + (size_t)(n0 + srow) * K + kbeg + spos * 8;
        gl16(ag, As + wave * 1024);
        gl16(ag + (size_t)16 * K, As + wave * 1024 + 512);
        gl16(bg, Bs + wave * 1024);
        gl16(bg + (size_t)16 * K, Bs + wave * 1024 + 512);
        WAIT_VM0_BARRIER();
        int cur = 0;
        for (int k0 = kbeg; k0 < kend; k0 += 32) {
            int koff = k0 + 32 - kbeg;
            if (k0 + 32 < kend) {
                int nb = cur ^ 1;
                gl16(ag + koff, As + nb * 4096 + wave * 1024);
                gl16(ag + koff + (size_t)16 * K, As + nb * 4096 + wave * 1024 + 512);
                gl16(bg + koff, Bs + nb * 4096 + wave * 1024);
                gl16(bg + koff + (size_t)16 * K, Bs + nb * 4096 + wave * 1024 + 512);
            }
            const unsigned short* Ab = As + cur * 4096;
            const unsigned short* Bb = Bs + cur * 4096;
            GEMM_COMPUTE(Ab, Bb);
            WAIT_VM0_BARRIER();
            cur ^= 1;
        }
    } else {
        int bn = t & 127, bkh = (t >> 7) << 4;
        for (int k0 = kbeg; k0 < kend; k0 += 32) {
            gl16(ag + (k0 - kbeg), As + wave * 1024);
            gl16(ag + (k0 - kbeg) + (size_t)16 * K, As + wave * 1024 + 512);
            const float* bp = Wf + (size_t)(k0 + bkh) * N + n0 + bn;
            unsigned int pk[8];
#pragma unroll
            for (int i = 0; i < 8; i++) {
                unsigned int lo = f2bfu(bp[(size_t)(2 * i) * N]);
                unsigned int hi = f2bfu(bp[(size_t)(2 * i + 1) * N]);
                pk[i] = lo | (hi << 16);
            }
            *(uint4*)&Bs[bn * 32 + bkh] = *(uint4*)&pk[0];
            *(uint4*)&Bs[bn * 32 + bkh + 8] = *(uint4*)&pk[4];
            __syncthreads();
            GEMM_COMPUTE(As, Bs);
            __syncthreads();
        }
    }
    float bj[4];
#pragma unroll
    for (int j = 0; j < 4; j++) bj[j] = (slice == 0) ? bias[n0 + wn + j * 16 + l16] : 0.f;
    float* outp = (slice == 0) ? Cf : Cf2;
#pragma unroll
    for (int i = 0; i < 4; i++)
#pragma unroll
        for (int j = 0; j < 4; j++) {
            int col = n0 + wn + j * 16 + l16;
#pragma unroll
            for (int r = 0; r < 4; r++) {
                int row = m0 + wm + i * 16 + quad * 4 + r;
                float v = acc[i][j][r] + bj[j];
                if (act) v = gelu_tanh(v);
                if (outp) outp[(size_t)row * N + col] = v;
                else      Cb[(size_t)row * N + col] = f2bfu(v);
            }
        }
}

// ---------------- legacy fused 5-way projection GEMM (fallback path) ----------------
__global__ __launch_bounds__(256) void k_gemm_qkv5(
    const unsigned short* __restrict__ A, P5 p) {
    __shared__ __align__(16) unsigned short As[2 * 128 * 32];
    __shared__ __align__(16) unsigned short Bs[2 * 128 * 32];
    int bx = blockIdx.x, by = blockIdx.y, bz = blockIdx.z;
    xcd_remap(bx, by, bz);
    const unsigned short* __restrict__ Wt = p.Wt[bz];
    const float* __restrict__ Wf = p.Wf[bz];
    const float* __restrict__ bias = p.bias[bz];
    unsigned short* __restrict__ Cb = p.out[bz];
    const int N = D_, K = D_;
    int t = threadIdx.x;
    int wave = t >> 6, lane = t & 63, l16 = lane & 15, quad = lane >> 4;
    int m0 = by << 7, n0 = bx << 7;
    int wm = (wave >> 1) << 6, wn = (wave & 1) << 6;
    f32x4 acc[4][4];
#pragma unroll
    for (int i = 0; i < 4; i++)
#pragma unroll
        for (int j = 0; j < 4; j++) acc[i][j] = (f32x4){0.f, 0.f, 0.f, 0.f};

    int ch = wave * 128 + lane;
    int srow = ch >> 2, spos = ch & 3;
    const unsigned short* ag = A + (size_t)(m0 + srow) * K + spos * 8;

    if (Wt) {
        const unsigned short* bg = Wt + (size_t)(n0 + srow) * K + spos * 8;
        gl16(ag, As + wave * 1024);
        gl16(ag + (size_t)16 * K, As + wave * 1024 + 512);
        gl16(bg, Bs + wave * 1024);
        gl16(bg + (size_t)16 * K, Bs + wave * 1024 + 512);
        WAIT_VM0_BARRIER();
        int cur = 0;
        for (int k0 = 0; k0 < K; k0 += 32) {
            int koff = k0 + 32;
            if (koff < K) {
                int nb = cur ^ 1;
                gl16(ag + koff, As + nb * 4096 + wave * 1024);
                gl16(ag + koff + (size_t)16 * K, As + nb * 4096 + wave * 1024 + 512);
                gl16(bg + koff, Bs + nb * 4096 + wave * 1024);
                gl16(bg + koff + (size_t)16 * K, Bs + nb * 4096 + wave * 1024 + 512);
            }
            const unsigned short* Ab = As + cur * 4096;
            const unsigned short* Bb = Bs + cur * 4096;
            GEMM_COMPUTE(Ab, Bb);
            WAIT_VM0_BARRIER();
            cur ^= 1;
        }
    } else {
        int bn = t & 127, bkh = (t >> 7) << 4;
        for (int k0 = 0; k0 < K; k0 += 32) {
            gl16(ag + k0, As + wave * 1024);
            gl16(ag + k0 + (size_t)16 * K, As + wave * 1024 + 512);
            const float* bp = Wf + (size_t)(k0 + bkh) * N + n0 + bn;
            unsigned int pk[8];
#pragma unroll
            for (int i = 0; i < 8; i++) {
                unsigned int lo = f2bfu(bp[(size_t)(2 * i) * N]);
                unsigned int hi = f2bfu(bp[(size_t)(2 * i + 1) * N]);
                pk[i] = lo | (hi << 16);
            }
            *(uint4*)&Bs[bn * 32 + bkh] = *(uint4*)&pk[0];
            *(uint4*)&Bs[bn * 32 + bkh + 8] = *(uint4*)&pk[4];
            __syncthreads();
            GEMM_COMPUTE(As, Bs);
            __syncthreads();
        }
    }
    float bj[4];
#pragma unroll
    for (int j = 0; j < 4; j++) bj[j] = bias[n0 + wn + j * 16 + l16];
#pragma unroll
    for (int i = 0; i < 4; i++)
#pragma unroll
        for (int j = 0; j < 4; j++) {
            int col = n0 + wn + j * 16 + l16;
#pragma unroll
            for (int r = 0; r < 4; r++) {
                int row = m0 + wm + i * 16 + quad * 4 + r;
                float v = acc[i][j][r] + bj[j];
                size_t adr = ((((size_t)(row >> 12)) * H_ + (col >> 6)) * S_ +
                              (row & (S_ - 1))) * DH_ + (col & 63);
                Cb[adr] = f2bfu(v);
            }
        }
}

// ---------------- MFMA flash local attention (64-row, dbuf K/V, 1 barrier/tile) ----------------
__global__ __launch_bounds__(256) void k_lattn(
    const unsigned short* __restrict__ q, const unsigned short* __restrict__ k,
    const unsigned short* __restrict__ v, const int* __restrict__ ids,
    const int* __restrict__ am, const int* __restrict__ idxg,
    unsigned short* __restrict__ Tb) {
    int s0 = blockIdx.x << 6, h = blockIdx.y, b = blockIdx.z;
    int t = threadIdx.x;
    int wave = t >> 6, lane = t & 63, l16 = lane & 15, quad = lane >> 4;

    __shared__ unsigned short Ks[2][64][72];
    __shared__ unsigned short Vt[2][64][72];   // swizzled d-major V tiles
    __shared__ unsigned short Ps[64][72];      // wave-private row stripes, no hazard
    __shared__ unsigned char keyok[2][64];

    const size_t headbase = (((size_t)b * H_) + h) * S_;
    int qrow = s0 + wave * 16 + l16;
    const unsigned short* qptr = q + (headbase + qrow) * DH_;
    short8 qa0 = *(const short8*)(qptr + quad * 8);
    short8 qa1 = *(const short8*)(qptr + 32 + quad * 8);

    f32x4 O[4];
#pragma unroll
    for (int nf = 0; nf < 4; nf++) O[nf] = (f32x4){0.f, 0.f, 0.f, 0.f};
    float m_run[4] = {-3.4e38f, -3.4e38f, -3.4e38f, -3.4e38f};
    float l_run[4] = {0.f, 0.f, 0.f, 0.f};

    int kbase = s0 - 256;
    int sr = t >> 2, sc = t & 3;

    uint4 k0v, k1v, v0v, v1v; bool okf = false;

    auto FETCH = [&](int tile) {
        int sK, sclamp;
        if (tile < 9) {
            sK = kbase + tile * 64 + sr;
            bool inr = (sK >= 0) && (sK < S_);
            sclamp = inr ? sK : 0;
            okf = inr && (am[b * S_ + sclamp] != 0) &&
                  !((ids[b * S_ + sclamp] == SEP_) || (sK == 0));
        } else {
            sclamp = idxg[b * G_ + sr];
            okf = true;
        }
        const unsigned short* srcK = k + (headbase + sclamp) * DH_;
        const unsigned short* srcV = v + (headbase + sclamp) * DH_;
        k0v = *(const uint4*)(srcK + sc * 8);
        k1v = *(const uint4*)(srcK + (sc + 4) * 8);
        v0v = *(const uint4*)(srcV + sc * 8);
        v1v = *(const uint4*)(srcV + (sc + 4) * 8);
    };
    auto WRITE = [&](int buf) {
        if (sc == 0) keyok[buf][sr] = okf ? 1 : 0;
        *(uint4*)&Ks[buf][sr][sc * 8] = k0v;
        *(uint4*)&Ks[buf][sr][(sc + 4) * 8] = k1v;
        STAGE_V_SWZ(Vt[buf], v0v, v1v, sr, sc);
    };

    FETCH(0); WRITE(0);
    __syncthreads();

    for (int tile = 0; tile < 10; tile++) {
        int cur = tile & 1;
        if (tile < 9) FETCH(tile + 1);   // loads in flight, hidden under compute

        f32x4 Sf[4];
#pragma unroll
        for (int nf = 0; nf < 4; nf++) {
            short8 b0 = *(const short8*)&Ks[cur][nf * 16 + l16][quad * 8];
            short8 b1 = *(const short8*)&Ks[cur][nf * 16 + l16][32 + quad * 8];
            f32x4 a = (f32x4){0.f, 0.f, 0.f, 0.f};
            a = __builtin_amdgcn_mfma_f32_16x16x32_bf16(qa0, b0, a, 0, 0, 0);
            a = __builtin_amdgcn_mfma_f32_16x16x32_bf16(qa1, b1, a, 0, 0, 0);
            Sf[nf] = a;
        }
        int ktb = kbase + tile * 64;
        bool kval[4];
#pragma unroll
        for (int nf = 0; nf < 4; nf++)
            kval[nf] = (tile == 9) || (keyok[cur][nf * 16 + l16] != 0);
        float P_[4][4];
        float mt[4];
#pragma unroll
        for (int r = 0; r < 4; r++) {
            int qs = s0 + wave * 16 + quad * 4 + r;
            float mx = -3.4e38f;
#pragma unroll
            for (int nf = 0; nf < 4; nf++) {
                int ks2 = ktb + nf * 16 + l16;
                bool ok = kval[nf] && ((tile == 9) || (ks2 >= qs - 256 && ks2 <= qs + 256));
                float sv = ok ? Sf[nf][r] * 0.125f : NEG_;
                P_[nf][r] = sv;
                mx = fmaxf(mx, sv);
            }
            mt[r] = mx;
        }
#pragma unroll
        for (int off = 1; off < 16; off <<= 1)
#pragma unroll
            for (int r = 0; r < 4; r++) mt[r] = fmaxf(mt[r], __shfl_xor(mt[r], off));
        float alpha[4], lt[4];
#pragma unroll
        for (int r = 0; r < 4; r++) {
            float mn = fmaxf(m_run[r], mt[r]);
            alpha[r] = __expf(m_run[r] - mn);
            m_run[r] = mn; lt[r] = 0.f;
        }
#pragma unroll
        for (int nf = 0; nf < 4; nf++)
#pragma unroll
            for (int r = 0; r < 4; r++) {
                float p = (P_[nf][r] > -1.0e8f) ? __expf(P_[nf][r] - m_run[r]) : 0.f;
                P_[nf][r] = p; lt[r] += p;
            }
#pragma unroll
        for (int off = 1; off < 16; off <<= 1)
#pragma unroll
            for (int r = 0; r < 4; r++) lt[r] += __shfl_xor(lt[r], off);
#pragma unroll
        for (int r = 0; r < 4; r++) l_run[r] = l_run[r] * alpha[r] + lt[r];
#pragma unroll
        for (int nf = 0; nf < 4; nf++) {
            O[nf][0] *= alpha[0]; O[nf][1] *= alpha[1];
            O[nf][2] *= alpha[2]; O[nf][3] *= alpha[3];
        }
#pragma unroll
        for (int nf = 0; nf < 4; nf++)
#pragma unroll
            for (int r = 0; r < 4; r++)
                Ps[wave * 16 + quad * 4 + r][nf * 16 + l16] = f2bfu(P_[nf][r]);
#pragma unroll
        for (int hh = 0; hh < 2; hh++) {
            short8 pa = *(const short8*)&Ps[wave * 16 + l16][hh * 32 + quad * 8];
#pragma unroll
            for (int nf = 0; nf < 4; nf++) {
                short8 vb8 = READ_V_SWZ(Vt[cur], nf * 16 + l16, hh);
                O[nf] = __builtin_amdgcn_mfma_f32_16x16x32_bf16(pa, vb8, O[nf], 0, 0, 0);
            }
        }
        if (tile < 9) WRITE(cur ^ 1);    // write-after-read safe: buf last read tile-1
        __syncthreads();
    }
#pragma unroll
    for (int r = 0; r < 4; r++) {
        int qs = s0 + wave * 16 + quad * 4 + r;
        float invl = 1.0f / l_run[r];
        size_t base = ((size_t)(b * S_ + qs)) * D_ + h * DH_;
#pragma unroll
        for (int nf = 0; nf < 4; nf++)
            Tb[base + nf * 16 + l16] = f2bfu(O[nf][r] * invl);
    }
}

// ---------------- MFMA global-query attention, pass 1 (pipelined) ----------------
__global__ __launch_bounds__(256) void k_gattn_part(
    const unsigned short* __restrict__ qg, const unsigned short* __restrict__ kga,
    const unsigned short* __restrict__ vga, const int* __restrict__ am,
    float* __restrict__ Opart, float* __restrict__ mbuf, float* __restrict__ lbuf) {
    int c = blockIdx.x, h = blockIdx.y, b = blockIdx.z;
    int t = threadIdx.x;
    int wave = t >> 6, lane = t & 63, l16 = lane & 15, quad = lane >> 4;

    __shared__ unsigned short Ks[2][64][72];
    __shared__ unsigned short Vt[2][64][72];
    __shared__ unsigned short Ps[64][72];
    __shared__ unsigned char keyok[2][64];

    const size_t headbase = (((size_t)b * H_) + h) * S_;
    int grow = wave * 16 + l16;
    const unsigned short* qptr = qg + ((size_t)(b * G_ + grow)) * D_ + h * DH_;
    short8 qa0 = *(const short8*)(qptr + quad * 8);
    short8 qa1 = *(const short8*)(qptr + 32 + quad * 8);

    f32x4 O[4];
#pragma unroll
    for (int nf = 0; nf < 4; nf++) O[nf] = (f32x4){0.f, 0.f, 0.f, 0.f};
    float m_run[4] = {-3.4e38f, -3.4e38f, -3.4e38f, -3.4e38f};
    float l_run[4] = {0.f, 0.f, 0.f, 0.f};

    int kbase = c * 256;
    int sr = t >> 2, sc = t & 3;

    uint4 k0v, k1v, v0v, v1v; bool okf = false;

    auto FETCH = [&](int tile) {
        int sK = kbase + tile * 64 + sr;
        okf = (am[b * S_ + sK] != 0);
        const unsigned short* srcK = kga + (headbase + sK) * DH_;
        const unsigned short* srcV = vga + (headbase + sK) * DH_;
        k0v = *(const uint4*)(srcK + sc * 8);
        k1v = *(const uint4*)(srcK + (sc + 4) * 8);
        v0v = *(const uint4*)(srcV + sc * 8);
        v1v = *(const uint4*)(srcV + (sc + 4) * 8);
    };
    auto WRITE = [&](int buf) {
        if (sc == 0) keyok[buf][sr] = okf ? 1 : 0;
        *(uint4*)&Ks[buf][sr][sc * 8] = k0v;
        *(uint4*)&Ks[buf][sr][(sc + 4) * 8] = k1v;
        STAGE_V_SWZ(Vt[buf], v0v, v1v, sr, sc);
    };

    FETCH(0); WRITE(0);
    __syncthreads();

    for (int tile = 0; tile < 4; tile++) {
        int cur = tile & 1;
        if (tile < 3) FETCH(tile + 1);

        f32x4 Sf[4];
#pragma unroll
        for (int nf = 0; nf < 4; nf++) {
            short8 b0 = *(const short8*)&Ks[cur][nf * 16 + l16][quad * 8];
            short8 b1 = *(const short8*)&Ks[cur][nf * 16 + l16][32 + quad * 8];
            f32x4 a = (f32x4){0.f, 0.f, 0.f, 0.f};
            a = __builtin_amdgcn_mfma_f32_16x16x32_bf16(qa0, b0, a, 0, 0, 0);
            a = __builtin_amdgcn_mfma_f32_16x16x32_bf16(qa1, b1, a, 0, 0, 0);
            Sf[nf] = a;
        }
        bool kval[4];
#pragma unroll
        for (int nf = 0; nf < 4; nf++) kval[nf] = (keyok[cur][nf * 16 + l16] != 0);
        float P_[4][4];
        float mt[4];
#pragma unroll
        for (int r = 0; r < 4; r++) {
            float mx = -3.4e38f;
#pragma unroll
            for (int nf = 0; nf < 4; nf++) {
                float sv = kval[nf] ? Sf[nf][r] * 0.125f : NEG_;
                P_[nf][r] = sv;
                mx = fmaxf(mx, sv);
            }
            mt[r] = mx;
        }
#pragma unroll
        for (int off = 1; off < 16; off <<= 1)
#pragma unroll
            for (int r = 0; r < 4; r++) mt[r] = fmaxf(mt[r], __shfl_xor(mt[r], off));
        float alpha[4], lt[4];
#pragma unroll
        for (int r = 0; r < 4; r++) {
            float mn = fmaxf(m_run[r], mt[r]);
            alpha[r] = __expf(m_run[r] - mn);
            m_run[r] = mn; lt[r] = 0.f;
        }
#pragma unroll
        for (int nf = 0; nf < 4; nf++)
#pragma unroll
            for (int r = 0; r < 4; r++) {
                float p = (P_[nf][r] > -1.0e8f) ? __expf(P_[nf][r] - m_run[r]) : 0.f;
                P_[nf][r] = p; lt[r] += p;
            }
#pragma unroll
        for (int off = 1; off < 16; off <<= 1)
#pragma unroll
            for (int r = 0; r < 4; r++) lt[r] += __shfl_xor(lt[r], off);
#pragma unroll
        for (int r = 0; r < 4; r++) l_run[r] = l_run[r] * alpha[r] + lt[r];
#pragma unroll
        for (int nf = 0; nf < 4; nf++) {
            O[nf][0] *= alpha[0]; O[nf][1] *= alpha[1];
            O[nf][2] *= alpha[2]; O[nf][3] *= alpha[3];
        }
#pragma unroll
        for (int nf = 0; nf < 4; nf++)
#pragma unroll
            for (int r = 0; r < 4; r++)
                Ps[wave * 16 + quad * 4 + r][nf * 16 + l16] = f2bfu(P_[nf][r]);
#pragma unroll
        for (int hh = 0; hh < 2; hh++) {
            short8 pa = *(const short8*)&Ps[wave * 16 + l16][hh * 32 + quad * 8];
#pragma unroll
            for (int nf = 0; nf < 4; nf++) {
                short8 vb8 = READ_V_SWZ(Vt[cur], nf * 16 + l16, hh);
                O[nf] = __builtin_amdgcn_mfma_f32_16x16x32_bf16(pa, vb8, O[nf], 0, 0, 0);
            }
        }
        if (tile < 3) WRITE(cur ^ 1);
        __syncthreads();
    }
    size_t bhc = ((size_t)(b * H_ + h)) * NC_ + c;
#pragma unroll
    for (int r = 0; r < 4; r++) {
        int row = wave * 16 + quad * 4 + r;
#pragma unroll
        for (int nf = 0; nf < 4; nf++)
            Opart[bhc * (G_ * DH_) + (size_t)row * DH_ + nf * 16 + l16] = O[nf][r];
        if (l16 == 0) {
            mbuf[bhc * G_ + row] = m_run[r];
            lbuf[bhc * G_ + row] = l_run[r];
        }
    }
}

// ---------------- global attention pass 2 ----------------
__global__ __launch_bounds__(64) void k_gattn_comb(
    const float* __restrict__ Opart, const float* __restrict__ mbuf,
    const float* __restrict__ lbuf, const int* __restrict__ idxg,
    unsigned short* __restrict__ Tb) {
    int g = blockIdx.x, h = blockIdx.y, b = blockIdx.z;
    int d = threadIdx.x;
    size_t bh = (size_t)(b * H_ + h);
    float M = -3.4e38f;
    float mv[NC_];
#pragma unroll
    for (int c = 0; c < NC_; c++) {
        mv[c] = mbuf[(bh * NC_ + c) * G_ + g];
        M = fmaxf(M, mv[c]);
    }
    float L = 0.f, o = 0.f;
#pragma unroll
    for (int c = 0; c < NC_; c++) {
        float e = __expf(mv[c] - M);
        L += lbuf[(bh * NC_ + c) * G_ + g] * e;
        o += Opart[(bh * NC_ + c) * (G_ * DH_) + (size_t)g * DH_ + d] * e;
    }
    int srow = idxg[b * G_ + g];
    Tb[((size_t)(b * S_ + srow)) * D_ + h * DH_ + d] = f2bfu(o / L);
}

// ---------------- VALU GEMM (small M); optional row gather via idxg from xsrc ----------------
__global__ __launch_bounds__(256) void k_gemm(
    const float* __restrict__ A, const float* __restrict__ Bw,
    const float* __restrict__ bias, float* __restrict__ Cf,
    unsigned short* __restrict__ Cb, int M, int N, int K, int act,
    const float* __restrict__ xsrc, const int* __restrict__ idxg) {
    __shared__ float As[16][68];
    __shared__ float Bs[16][68];
    int tl = threadIdx.x;
    int tx = tl & 15, ty = tl >> 4;
    int m0 = blockIdx.y << 6, n0 = blockIdx.x << 6;
    float c[4][4] = {{0.f}};
    int arow = tl >> 2, akk = (tl & 3) << 2;
    int bkk = tl >> 4, bcol = (tl & 15) << 2;
    const float* arow_p;
    if (idxg) {
        int bg = m0 + arow;
        int bb = bg >> 6;                 // G_ = 64
        int srow = idxg[bg];
        arow_p = xsrc + ((size_t)(bb * S_ + srow)) * D_;
    } else {
        arow_p = A + (size_t)(m0 + arow) * K;
    }
    for (int k0 = 0; k0 < K; k0 += 16) {
        float4 a4 = *(const float4*)(arow_p + k0 + akk);
        As[akk + 0][arow] = a4.x; As[akk + 1][arow] = a4.y;
        As[akk + 2][arow] = a4.z; As[akk + 3][arow] = a4.w;
        float4 b4 = *(const float4*)(Bw + (size_t)(k0 + bkk) * N + n0 + bcol);
        Bs[bkk][bcol + 0] = b4.x; Bs[bkk][bcol + 1] = b4.y;
        Bs[bkk][bcol + 2] = b4.z; Bs[bkk][bcol + 3] = b4.w;
        __syncthreads();
#pragma unroll
        for (int kk = 0; kk < 16; kk++) {
            float4 av = *(const float4*)&As[kk][ty << 2];
            float4 bv = *(const float4*)&Bs[kk][tx << 2];
            float aa[4] = {av.x, av.y, av.z, av.w};
            float bb[4] = {bv.x, bv.y, bv.z, bv.w};
#pragma unroll
            for (int i = 0; i < 4; i++)
#pragma unroll
                for (int j = 0; j < 4; j++) c[i][j] += aa[i] * bb[j];
        }
        __syncthreads();
    }
    float bias4[4];
#pragma unroll
    for (int j = 0; j < 4; j++) bias4[j] = bias[n0 + (tx << 2) + j];
#pragma unroll
    for (int i = 0; i < 4; i++) {
        int mrow = m0 + (ty << 2) + i;
        float v0 = c[i][0] + bias4[0], v1 = c[i][1] + bias4[1];
        float v2 = c[i][2] + bias4[2], v3 = c[i][3] + bias4[3];
        if (act) { v0 = gelu_tanh(v0); v1 = gelu_tanh(v1); v2 = gelu_tanh(v2); v3 = gelu_tanh(v3); }
        if (Cf) {
            float4 o; o.x = v0; o.y = v1; o.z = v2; o.w = v3;
            *(float4*)(Cf + (size_t)mrow * N + n0 + (tx << 2)) = o;
        } else {
            ushort4 o; o.x = f2bfu(v0); o.y = f2bfu(v1); o.z = f2bfu(v2); o.w = f2bfu(v3);
            *(ushort4*)(Cb + (size_t)mrow * N + n0 + (tx << 2)) = o;
        }
    }
}

// ---------------- classifier ----------------
__global__ __launch_bounds__(256) void k_classifier(
    const float* __restrict__ x, const float* __restrict__ Wc,
    const float* __restrict__ bc, const int* __restrict__ lo_p,
    int rows_pb, float* __restrict__ out) {
    int r = blockIdx.x;
    int b = r / rows_pb, i = r % rows_pb;
    int s = lo_p[0] + i;
    int t = threadIdx.x;
    __shared__ float xr[D_];
    __shared__ float red[256];
    const float* xrow = x + ((size_t)(b * S_ + s)) * D_;
    for (int d = t; d < D_; d += 256) xr[d] = xrow[d];
    __syncthreads();
    for (int c = 0; c < C_; c++) {
        float loc = 0.f;
        for (int d = t; d < D_; d += 256) loc += xr[d] * Wc[d * C_ + c];
        red[t] = loc; __syncthreads();
        for (int o = 128; o; o >>= 1) { if (t < o) red[t] += red[t + o]; __syncthreads(); }
        if (t == 0) out[r * C_ + c] = red[0] + bc[c];
        __syncthreads();
    }
}

extern "C" void kernel_launch(void* const* d_in, const int* in_sizes, int n_in,
                              void* d_out, int out_size, void* d_ws, size_t ws_size,
                              hipStream_t stream) {
    (void)in_sizes; (void)n_in;
    const float* emb_tok = (const float*)d_in[0];
    const float* emb_pos = (const float*)d_in[1];
    const float* ln_e_s = (const float*)d_in[2];
    const float* ln_e_b = (const float*)d_in[3];
    const float* Wq  = (const float*)d_in[4];
    const float* bq  = (const float*)d_in[5];
    const float* Wk  = (const float*)d_in[6];
    const float* bk  = (const float*)d_in[7];
    const float* Wv  = (const float*)d_in[8];
    const float* bv  = (const float*)d_in[9];
    const float* Wqg = (const float*)d_in[10];
    const float* bqg = (const float*)d_in[11];
    const float* Wkg = (const float*)d_in[12];
    const float* bkg = (const float*)d_in[13];
    const float* Wvg = (const float*)d_in[14];
    const float* bvg = (const float*)d_in[15];
    const float* Wo  = (const float*)d_in[16];
    const float* bo  = (const float*)d_in[17];
    const float* ln1_s = (const float*)d_in[18];
    const float* ln1_b = (const float*)d_in[19];
    const float* Wf1 = (const float*)d_in[20];
    const float* bf1 = (const float*)d_in[21];
    const float* Wf2 = (const float*)d_in[22];
    const float* bf2 = (const float*)d_in[23];
    const float* ln2_s = (const float*)d_in[24];
    const float* ln2_b = (const float*)d_in[25];
    const float* Wc  = (const float*)d_in[26];
    const float* bc  = (const float*)d_in[27];
    const int* input_ids = (const int*)d_in[28];
    const int* attn_mask = (const int*)d_in[29];
    const int* lo        = (const int*)d_in[30];

    const size_t SZB = (size_t)B_ * S_ * D_;
    const size_t D2 = (size_t)D_ * D_;
    const size_t PL = 6 * D2 + 2 * (size_t)D_ * FF_;   // bf16 weight elems per layer
    uint8_t* w = (uint8_t*)d_ws;
    float*          x    = (float*)w;
    unsigned short* xb   = (unsigned short*)(w + 4 * SZB);
    float*          P    = (float*)(w + 6 * SZB);
    unsigned short* qb   = (unsigned short*)(w + 10 * SZB);
    unsigned short* kb   = (unsigned short*)(w + 12 * SZB);
    unsigned short* vb   = (unsigned short*)(w + 14 * SZB);
    unsigned short* kgab = (unsigned short*)(w + 16 * SZB);
    unsigned short* vgab = (unsigned short*)(w + 18 * SZB);
    unsigned short* Hb   = (unsigned short*)(w + 10 * SZB);
    unsigned short* Tb   = (unsigned short*)(w + 20 * SZB);
    unsigned short* qgb = (unsigned short*)(w + 22 * SZB + (size_t)B_ * G_ * D_ * 4);
    int* idxg = (int*)(w + 22 * SZB + (size_t)B_ * G_ * D_ * 4 + (size_t)B_ * G_ * D_ * 2);
    float* Opart = (float*)(w + 23 * SZB);
    float* mbuf  = (float*)(w + 24 * SZB);
    float* lbuf  = mbuf + (size_t)B_ * H_ * NC_ * G_;

    const size_t P2_OFF = 24 * SZB + (1u << 20);
    const size_t WB_OFF = P2_OFF + 4 * SZB;
    const size_t NEED_P2 = WB_OFF;
    const size_t NEED_W = WB_OFF + L_ * PL * 2;
    float* P2 = (float*)(w + P2_OFF);
    unsigned short* wb = (unsigned short*)(w + WB_OFF);
    const int useW = (ws_size >= NEED_W) ? 1 : 0;
    const int useSplit = (ws_size >= NEED_P2) ? 1 : 0;

    const int BS = B_ * S_;

    if (useW) {
        WT8 wt;
        int cum = 0;
        auto addop = [&](int opi, const float* s, unsigned short* d, int K, int N) {
            wt.src[opi] = s; wt.dst[opi] = d; wt.K[opi] = K; wt.N[opi] = N;
            wt.cum[opi] = cum; cum += L_ * (N / 32) * (K / 32);
        };
        addop(0, Wq,  wb + 0 * D2, D_, D_);
        addop(1, Wk,  wb + 1 * D2, D_, D_);
        addop(2, Wv,  wb + 2 * D2, D_, D_);
        addop(3, Wkg, wb + 3 * D2, D_, D_);
        addop(4, Wvg, wb + 4 * D2, D_, D_);
        addop(5, Wo,  wb + 5 * D2, D_, D_);
        addop(6, Wf1, wb + 6 * D2, D_, FF_);
        addop(7, Wf2, wb + 6 * D2 + (size_t)D_ * FF_, FF_, D_);
        wt.cum[8] = cum;
        k_wtrans_all<<<cum, 256, 0, stream>>>(wt, PL);
    }

    k_embed_ln<<<BS / 4, 256, 0, stream>>>(input_ids, emb_tok, emb_pos, ln_e_s, ln_e_b, x, xb);
    k_idx<<<B_, 256, 0, stream>>>(input_ids, idxg);

    dim3 g_ds(D_ / 128, BS / 128, useSplit ? 2 : 1);    // legacy split-K variant
    dim3 g_d5(D_ / 128, BS / 128, 5);
    dim3 g_ff(FF_ / 128, BS / 128);
    dim3 g_qg(D_ / 64, (B_ * G_) / 64);

    for (int l = 0; l < L_; l++) {
        const unsigned short* wbl = wb + (size_t)l * PL;
        P5 p5;
        p5.Wf[0] = Wq  + (size_t)l * D2;  p5.bias[0] = bq  + l * D_;  p5.out[0] = qb;
        p5.Wf[1] = Wk  + (size_t)l * D2;  p5.bias[1] = bk  + l * D_;  p5.out[1] = kb;
        p5.Wf[2] = Wv  + (size_t)l * D2;  p5.bias[2] = bv  + l * D_;  p5.out[2] = vb;
        p5.Wf[3] = Wkg + (size_t)l * D2;  p5.bias[3] = bkg + l * D_;  p5.out[3] = kgab;
        p5.Wf[4] = Wvg + (size_t)l * D2;  p5.bias[4] = bvg + l * D_;  p5.out[4] = vgab;
        for (int i = 0; i < 5; i++) p5.Wt[i] = useW ? (wbl + (size_t)i * D2) : nullptr;
        const float* Wqg_l = Wqg + (size_t)l * D2;
        const float* Wo_l  = Wo  + (size_t)l * D2;
        const float* Wf1_l = Wf1 + (size_t)l * D_ * FF_;
        const float* Wf2_l = Wf2 + (size_t)l * FF_ * D_;
        const unsigned short* Wo_t  = useW ? (wbl + 5 * D2) : nullptr;
        const unsigned short* Wf1_t = useW ? (wbl + 6 * D2) : nullptr;
        const unsigned short* Wf2_t = useW ? (wbl + 6 * D2 + (size_t)D_ * FF_) : nullptr;

        if (useW) {
            k_qkv5_256<<<dim3(D_ / 256, BS / 256, 5), 512, 0, stream>>>(xb, p5);
        } else {
            k_gemm_qkv5<<<g_d5, 256, 0, stream>>>(xb, p5);
        }
        k_lattn<<<dim3(S_ / 64, H_, B_), 256, 0, stream>>>(qb, kb, vb, input_ids, attn_mask, idxg, Tb);
        k_gemm<<<g_qg, 256, 0, stream>>>(nullptr, Wqg_l, bqg + l * D_, nullptr, qgb, B_ * G_, D_, D_, 0, x, idxg);
        k_gattn_part<<<dim3(NC_, H_, B_), 256, 0, stream>>>(qgb, kgab, vgab, attn_mask, Opart, mbuf, lbuf);
        k_gattn_comb<<<dim3(G_, H_, B_), 64, 0, stream>>>(Opart, mbuf, lbuf, idxg, Tb);
        if (useW) {
            k_gemm256_nt<<<dim3(D_ / 256, BS / 256, useSplit ? 2 : 1), 512, 0, stream>>>(
                Tb, Wo_t, bo + l * D_, P, P2, nullptr, BS, D_, D_, 0);
            k_add_ln<<<BS / 4, 256, 0, stream>>>(x, P, useSplit ? P2 : nullptr, ln1_s + l * D_, ln1_b + l * D_, xb);
            k_gemm256_nt<<<dim3(FF_ / 256, BS / 256, 1), 512, 0, stream>>>(
                xb, Wf1_t, bf1 + l * FF_, nullptr, nullptr, Hb, BS, FF_, D_, 1);
            k_gemm256_nt<<<dim3(D_ / 256, BS / 256, useSplit ? 2 : 1), 512, 0, stream>>>(
                Hb, Wf2_t, bf2 + l * D_, P, P2, nullptr, BS, D_, FF_, 0);
            k_add_ln<<<BS / 4, 256, 0, stream>>>(x, P, useSplit ? P2 : nullptr, ln2_s + l * D_, ln2_b + l * D_, xb);
        } else {
            k_gemm_mfma<<<g_ds, 256, 0, stream>>>(Tb, Wo_t, Wo_l, bo + l * D_, P, P2, nullptr, BS, D_, D_, 0);
            k_add_ln<<<BS / 4, 256, 0, stream>>>(x, P, useSplit ? P2 : nullptr, ln1_s + l * D_, ln1_b + l * D_, xb);
            k_gemm_mfma<<<g_ff, 256, 0, stream>>>(xb, Wf1_t, Wf1_l, bf1 + l * FF_, nullptr, nullptr, Hb, BS, FF_, D_, 1);
            k_gemm_mfma<<<g_ds, 256, 0, stream>>>(Hb, Wf2_t, Wf2_l, bf2 + l * D_, P, P2, nullptr, BS, D_, FF_, 0);
            k_add_ln<<<BS / 4, 256, 0, stream>>>(x, P, useSplit ? P2 : nullptr, ln2_s + l * D_, ln2_b + l * D_, xb);
        }
    }

    int rows = out_size / C_;
    int rows_pb = rows / B_;
    k_classifier<<<rows, 256, 0, stream>>>(x, Wc, bc, lo, rows_pb, (float*)d_out);
}